// Round 10
// baseline (223.853 us; speedup 1.0000x reference)
//
#include <hip/hip_runtime.h>
#include <hip/hip_bf16.h>

// mLSTM parallel-stabilized cell, MI355X (gfx950).
// B=2, S=2048, H=1024, NH=4, DH=256.
// Identity: max_log_D[i] = cs[i] + m[i], m[i] = prefixmax(ig[j]-cs[j]);
// D[i][j] = exp(a[j]-m[i]), a[j] = ig[j]-cs[j], exponent always <= 0.
// R10: main split into (bh, it, 512-key chunk) partials — 640 uniform blocks,
// largest-first; R6 inner loop VERBATIM; single-buffer LDS (69 KB -> 2
// blocks/CU) with plain __syncthreads; fp32 atomic O/rowsum accumulation
// (R2-R4-proven bit-stable) + R4's finalize kernel. Prep/scan = R9 verbatim.

#define S_LEN 2048
#define DHD   256
#define NHEAD 4
#define BATCH 2
#define HID   1024
#define BH_CNT (BATCH*NHEAD)

typedef __attribute__((ext_vector_type(8))) short bf16x8;
typedef __attribute__((ext_vector_type(4))) short short4v;
typedef __attribute__((ext_vector_type(4))) float f32x4;

static __device__ __forceinline__ short f2b(float f) {
  __hip_bfloat16 h = __float2bfloat16(f);
  return *reinterpret_cast<short*>(&h);
}

static __device__ __forceinline__ bf16x8 pack8(f32x4 a, f32x4 b) {
  bf16x8 o;
  o[0]=f2b(a[0]); o[1]=f2b(a[1]); o[2]=f2b(a[2]); o[3]=f2b(a[3]);
  o[4]=f2b(b[0]); o[5]=f2b(b[1]); o[6]=f2b(b[2]); o[7]=f2b(b[3]);
  return o;
}

// async global->LDS DMA, 16B/lane. ldsdst wave-uniform; lane l -> dst + l*16B.
static __device__ __forceinline__ void gload16(const void* src, void* ldsdst) {
  __builtin_amdgcn_global_load_lds(
      (const __attribute__((address_space(1))) void*)src,
      (__attribute__((address_space(3))) void*)ldsdst, 16, 0, 0);
}

// ---- kernel 1 (prep): grid 6144 x 256. (verbatim R9)
// bx <  2048 : merged gates (q+k+v parts, 2 rows) + k cast->Kg (swizzled)
// bx <  6144 : v transpose->Vg (swizzled), gate-free
// Kg tile [bh][jt][32x256]: (r,d) at r*256 + (d ^ ((r&7)<<3)).
// Vg tile [bh][jt][256x32]: (d,j) at d*32 + (j ^ (((d>>1)&3)<<3)).
__global__ __launch_bounds__(256) void prep_kernel(
    const float* __restrict__ q, const float* __restrict__ k, const float* __restrict__ v,
    const float* __restrict__ wi, const float* __restrict__ wf,
    short* __restrict__ Kg, short* __restrict__ Vg,
    float* __restrict__ igA, float* __restrict__ fgA) {
  __shared__ short vtile[32][33];
  const int bx = blockIdx.x, t = threadIdx.x;
  if (bx < 2048) {
    const int g_row = bx * 2 + (t >> 7);
    const int col = (t & 127) * 8;
    const long off = (long)g_row*HID + col;
    const f32x4 xq0 = *(const f32x4*)(q + off);
    const f32x4 xq1 = *(const f32x4*)(q + off + 4);
    const f32x4 xk0 = *(const f32x4*)(k + off);
    const f32x4 xk1 = *(const f32x4*)(k + off + 4);
    const f32x4 xv0 = *(const f32x4*)(v + off);
    const f32x4 xv1 = *(const f32x4*)(v + off + 4);
    f32x4 ai = {0.f,0.f,0.f,0.f}, af = {0.f,0.f,0.f,0.f};
#pragma unroll
    for (int j = 0; j < 4; j++) {
      ai += xq0[j] * *(const f32x4*)(wi + (long)(col + j)*4);
      af += xq0[j] * *(const f32x4*)(wf + (long)(col + j)*4);
      ai += xq1[j] * *(const f32x4*)(wi + (long)(col + 4 + j)*4);
      af += xq1[j] * *(const f32x4*)(wf + (long)(col + 4 + j)*4);
      ai += xk0[j] * *(const f32x4*)(wi + (long)(HID + col + j)*4);
      af += xk0[j] * *(const f32x4*)(wf + (long)(HID + col + j)*4);
      ai += xk1[j] * *(const f32x4*)(wi + (long)(HID + col + 4 + j)*4);
      af += xk1[j] * *(const f32x4*)(wf + (long)(HID + col + 4 + j)*4);
      ai += xv0[j] * *(const f32x4*)(wi + (long)(2*HID + col + j)*4);
      af += xv0[j] * *(const f32x4*)(wf + (long)(2*HID + col + j)*4);
      ai += xv1[j] * *(const f32x4*)(wi + (long)(2*HID + col + 4 + j)*4);
      af += xv1[j] * *(const f32x4*)(wf + (long)(2*HID + col + 4 + j)*4);
    }
    {
      bf16x8 o = pack8(xk0, xk1);
      const int b = g_row >> 11, s = g_row & (S_LEN-1);
      const int hh = col >> 8, d = col & 255;
      const int bh = b*NHEAD + hh, jt = s >> 5, rr = s & 31;
      *(bf16x8*)(Kg + ((long)bh*64 + jt)*8192 + rr*256 + (d ^ ((rr & 7) << 3))) = o;
    }
    for (int mk = 32; mk >= 1; mk >>= 1) {
#pragma unroll
      for (int e = 0; e < 4; e++) {
        ai[e] += __shfl_xor(ai[e], mk);
        af[e] += __shfl_xor(af[e], mk);
      }
    }
    if ((t & 63) == 0) {
#pragma unroll
      for (int e = 0; e < 4; e++) {
        unsafeAtomicAdd(&igA[(long)g_row*NHEAD + e], ai[e]);
        unsafeAtomicAdd(&fgA[(long)g_row*NHEAD + e], af[e]);
      }
    }
  } else {
    const int t2 = bx - 2048;
    const int d0 = (t2 & 7) * 32, j0 = ((t2 >> 3) & 63) * 32, bhv = t2 >> 9;
    const int b = bhv >> 2, hh = bhv & 3;
    const int c = t & 31, rr = t >> 5;
#pragma unroll
    for (int kk = 0; kk < 32; kk += 8)
      vtile[rr + kk][c] = f2b(v[((long)(b*S_LEN + j0 + rr + kk))*HID + hh*DHD + d0 + c]);
    __syncthreads();
    const long base = ((long)bhv*64 + (j0 >> 5)) * 8192;
#pragma unroll
    for (int kk = 0; kk < 32; kk += 8) {
      const int d = d0 + rr + kk;
      Vg[base + (long)d*32 + (c ^ (((d >> 1) & 3) << 3))] = vtile[c][rr + kk];
    }
  }
}

// ---- kernel 2: per-(b,h) scan (verbatim R9) ----
__global__ void scan_kernel(const float* __restrict__ ig, const float* __restrict__ fg,
                            const float* __restrict__ bi, const float* __restrict__ bf_,
                            float* __restrict__ a_out, float* __restrict__ m_out,
                            float* __restrict__ nf_out) {
  int bh = blockIdx.x, b = bh >> 2, h = bh & 3;
  int t = threadIdx.x;
  __shared__ float tot[256];
  long gbase = (long)b * S_LEN;
  const float biv = bi[h], bfv = bf_[h];
  float ls[8];
  float run = 0.f;
  for (int e = 0; e < 8; e++) {
    int s = t*8 + e;
    float x = fg[(gbase + s)*NHEAD + h] + bfv;
    float l = fminf(x, 0.f) - log1pf(expf(-fabsf(x)));  // stable log_sigmoid
    run += l; ls[e] = run;
  }
  tot[t] = run;
  __syncthreads();
  for (int off = 1; off < 256; off <<= 1) {
    float x = tot[t];
    if (t >= off) x += tot[t - off];
    __syncthreads();
    tot[t] = x;
    __syncthreads();
  }
  float offc = (t == 0) ? 0.f : tot[t-1];
  __syncthreads();
  float av[8], am[8], csv[8];
  float runm = -1e30f;
  for (int e = 0; e < 8; e++) {
    int s = t*8 + e;
    float cs = ls[e] + offc;
    csv[e] = cs;
    float a = (ig[(gbase + s)*NHEAD + h] + biv) - cs;
    av[e] = a;
    runm = fmaxf(runm, a);
    am[e] = runm;
  }
  tot[t] = runm;
  __syncthreads();
  for (int off = 1; off < 256; off <<= 1) {
    float x = tot[t];
    if (t >= off) x = fmaxf(x, tot[t - off]);
    __syncthreads();
    tot[t] = x;
    __syncthreads();
  }
  float offm = (t == 0) ? -1e30f : tot[t-1];
  long obase = (long)bh * S_LEN;
  for (int e = 0; e < 8; e++) {
    int s = t*8 + e;
    float mm = fmaxf(am[e], offm);
    a_out[obase + s]  = av[e];
    m_out[obase + s]  = mm;
    nf_out[obase + s] = expf(-(csv[e] + mm));
  }
}

// ---- kernel 3: partial main. 640 blocks = (bh, it, 512-key chunk), uniform
// <=8 periods, largest-first. R6 inner loop verbatim; single-buffer LDS;
// atomic O/rowsum accumulation into outp/rsacc. ----
__global__ __launch_bounds__(256, 2) void mlstm_partial_kernel(
    const float* __restrict__ q, const short* __restrict__ Kg, const short* __restrict__ Vg,
    const float* __restrict__ a_arr, const float* __restrict__ m_arr,
    float* __restrict__ outp, float* __restrict__ rsacc) {
  __shared__ alignas(16) short KVst[4][8192];   // [K0,K1,V0,V1] 16KB tiles
  __shared__ alignas(16) short plds[4][16*36];
  __shared__ float rsl[64];
  const int w = threadIdx.x >> 6, lane = threadIdx.x & 63;
  const int lr = lane & 15, g = lane >> 4;
  const int rg2 = w >> 1, kp = w & 1;
  const int bh = blockIdx.x & 7;
  int cidx = blockIdx.x >> 3;
  int it = 31;                                   // largest-first decode
  while (cidx >= ((it >> 3) + 1)) { cidx -= (it >> 3) + 1; --it; }
  const int jc = cidx;
  const int b = bh >> 2, h = bh & 3;
  const int R0 = it*64 + rg2*32;                 // wave's first global row
  const long arow = (long)bh * S_LEN;
  const int jt0 = jc * 16;                       // first 32-key tile of chunk
  const int kend = min(jc*512 + 512, (it+1)*64);
  const int np = (kend - jc*512) >> 6;           // 64-key periods in chunk
  const int ntw = it*2 + rg2 + 1;                // wave computes jtc < ntw
  const f32x4 zz = {0.f,0.f,0.f,0.f};
  const int sw = (lr & 7) << 3;

  // Q fragments for the wave's 32 rows, cast inline from fp32 source
  bf16x8 qfa[8], qfb[8];
  const float* qsrc = q + ((long)(b*S_LEN + R0 + lr))*HID + h*DHD + g*8;
#pragma unroll
  for (int c8 = 0; c8 < 8; c8++) {
    f32x4 u0 = *(const f32x4*)(qsrc + c8*32);
    f32x4 u1 = *(const f32x4*)(qsrc + c8*32 + 4);
    f32x4 w0 = *(const f32x4*)(qsrc + 16*HID + c8*32);
    f32x4 w1 = *(const f32x4*)(qsrc + 16*HID + c8*32 + 4);
    qfa[c8] = pack8(u0, u1);
    qfb[c8] = pack8(w0, w1);
  }
  float ma[4], mb[4];
#pragma unroll
  for (int r = 0; r < 4; r++) {
    ma[r] = m_arr[arow + R0 + g*4 + r];
    mb[r] = m_arr[arow + R0 + 16 + g*4 + r];
  }

  f32x4 oa[16], ob[16];
#pragma unroll
  for (int t = 0; t < 16; t++) { oa[t] = zz; ob[t] = zz; }
  float rs_a[4] = {0,0,0,0}, rs_b[4] = {0,0,0,0};
  short* myp = plds[w];

  for (int p = 0; p < np; ++p) {
    // stage: waves 0,1 -> K parities 0,1; waves 2,3 -> V parities 0,1
    {
      const int jts = jt0 + 2*p + (w & 1);
      short* dst = &KVst[(w < 2 ? 0 : 2) + (w & 1)][0];
      const short* src = ((w < 2) ? Kg : Vg) + ((long)bh*64 + jts)*8192 + lane*8;
#pragma unroll
      for (int u = 0; u < 16; u++)
        gload16(src + u*512, dst + u*512);
    }
    __syncthreads();   // drains vmcnt(0): tiles ready

    const int jtc = jt0 + 2*p + kp;
    if (jtc < ntw) {
      const int j0 = jtc*32;
      const short* Kt = &KVst[kp][0];
      const short* Vt = &KVst[2 + kp][0];
      f32x4 s0a = zz, s1a = zz, s0b = zz, s1b = zz;
      __builtin_amdgcn_s_setprio(1);
#pragma unroll
      for (int c8 = 0; c8 < 8; c8++) {
        const int ko = lr*256 + ((c8*32 + g*8) ^ sw);
        bf16x8 k0 = *(const bf16x8*)&Kt[ko];
        bf16x8 k1 = *(const bf16x8*)&Kt[ko + 4096];
        s0a = __builtin_amdgcn_mfma_f32_16x16x32_bf16(qfa[c8], k0, s0a, 0, 0, 0);
        s0b = __builtin_amdgcn_mfma_f32_16x16x32_bf16(qfb[c8], k0, s0b, 0, 0, 0);
        s1a = __builtin_amdgcn_mfma_f32_16x16x32_bf16(qfa[c8], k1, s1a, 0, 0, 0);
        s1b = __builtin_amdgcn_mfma_f32_16x16x32_bf16(qfb[c8], k1, s1b, 0, 0, 0);
      }
      __builtin_amdgcn_s_setprio(0);
      const float a0 = a_arr[arow + j0 + lr];
      const float a1 = a_arr[arow + j0 + 16 + lr];
      // ---- group a: P + re-fragment ----
      bf16x8 pa_a, pa_b;
      {
        const bool needmask = (j0 + 31 > R0);
#pragma unroll
        for (int r = 0; r < 4; r++) {
          const int i = R0 + g*4 + r;
          float p0 = s0a[r] * 0.0625f * __expf(a0 - ma[r]);
          float p1 = s1a[r] * 0.0625f * __expf(a1 - ma[r]);
          if (needmask) {
            if (j0 + lr > i)      p0 = 0.f;
            if (j0 + 16 + lr > i) p1 = 0.f;
          }
          rs_a[r] += p0 + p1;
          myp[(g*4 + r)*36 + lr]      = f2b(p0);
          myp[(g*4 + r)*36 + 16 + lr] = f2b(p1);
        }
        const short* rp = myp + lr*36 + g*8;
        short4v plo = *(const short4v*)rp;
        short4v phi = *(const short4v*)(rp + 4);
        pa_a = bf16x8{plo[0],plo[1],plo[2],plo[3],phi[0],phi[1],phi[2],phi[3]};
      }
      // ---- group b ----
      {
        const bool needmask = (j0 + 31 > R0 + 16);
#pragma unroll
        for (int r = 0; r < 4; r++) {
          const int i = R0 + 16 + g*4 + r;
          float p0 = s0b[r] * 0.0625f * __expf(a0 - mb[r]);
          float p1 = s1b[r] * 0.0625f * __expf(a1 - mb[r]);
          if (needmask) {
            if (j0 + lr > i)      p0 = 0.f;
            if (j0 + 16 + lr > i) p1 = 0.f;
          }
          rs_b[r] += p0 + p1;
          myp[(g*4 + r)*36 + lr]      = f2b(p0);
          myp[(g*4 + r)*36 + 16 + lr] = f2b(p1);
        }
        const short* rp = myp + lr*36 + g*8;
        short4v plo = *(const short4v*)rp;
        short4v phi = *(const short4v*)(rp + 4);
        pa_b = bf16x8{plo[0],plo[1],plo[2],plo[3],phi[0],phi[1],phi[2],phi[3]};
      }
      // ---- PV: read each V fragment ONCE, feed both row groups ----
      __builtin_amdgcn_s_setprio(1);
#pragma unroll
      for (int t = 0; t < 16; t++) {
        const int d = t*16 + lr;
        const int vo = d*32 + ((g*8) ^ (((d >> 1) & 3) << 3));
        bf16x8 vf = *(const bf16x8*)&Vt[vo];
        oa[t] = __builtin_amdgcn_mfma_f32_16x16x32_bf16(pa_a, vf, oa[t], 0, 0, 0);
        ob[t] = __builtin_amdgcn_mfma_f32_16x16x32_bf16(pa_b, vf, ob[t], 0, 0, 0);
      }
      __builtin_amdgcn_s_setprio(0);
    }
    __syncthreads();   // all reads done before buffer reuse
  }

  // ---- rowsum reduce over the 16 key-columns ----
#pragma unroll
  for (int r = 0; r < 4; r++)
    for (int mk = 1; mk < 16; mk <<= 1) {
      rs_a[r] += __shfl_xor(rs_a[r], mk);
      rs_b[r] += __shfl_xor(rs_b[r], mk);
    }

  // ---- combine key-parities via LDS (kp=1 writes, kp=0 adds + atomics) ----
  float* Ols = (float*)&KVst[0][0];   // 64 rows x 256 d fp32 = 64 KB
  __syncthreads();
  if (kp == 1) {
#pragma unroll
    for (int r = 0; r < 4; r++) {
      const int rla = rg2*32 + g*4 + r, rlb = rla + 16;
#pragma unroll
      for (int t = 0; t < 16; t++) {
        Ols[(long)rla*256 + t*16 + lr] = oa[t][r];
        Ols[(long)rlb*256 + t*16 + lr] = ob[t][r];
      }
      if (lr == 0) { rsl[rla] = rs_a[r]; rsl[rlb] = rs_b[r]; }
    }
  }
  __syncthreads();
  if (kp == 0) {
    for (int grp = 0; grp < 2; grp++) {
      f32x4* acc = grp ? ob : oa;
      float* rsv = grp ? rs_b : rs_a;
#pragma unroll
      for (int r = 0; r < 4; r++) {
        const int rl = rg2*32 + grp*16 + g*4 + r;
        const int i = R0 + grp*16 + g*4 + r;
        float* orow = outp + ((long)(b*S_LEN + i))*HID + h*DHD + lr;
#pragma unroll
        for (int t = 0; t < 16; t++)
          unsafeAtomicAdd(orow + t*16, acc[t][r] + Ols[(long)rl*256 + t*16 + lr]);
        if (lr == 0)
          unsafeAtomicAdd(&rsacc[arow + i], rsv[r] + rsl[rl]);
      }
    }
  }
}

// ---- kernel 4: finalize — normalizer + per-head LayerNorm (verbatim R4) ----
__global__ __launch_bounds__(256) void finalize_kernel(
    float* __restrict__ outp, const float* __restrict__ rsacc,
    const float* __restrict__ nf_arr, const float* __restrict__ lns) {
  const int bi = blockIdx.x;                  // b*S + i
  const int h = threadIdx.x >> 6, lane = threadIdx.x & 63;
  const int b = bi >> 11, i = bi & (S_LEN-1);
  const int bh = b*NHEAD + h;
  const long roff = (long)bi * HID + (long)h*DHD;
  f32x4 xv = *(const f32x4*)(outp + roff + lane*4);
  const float rsv = rsacc[(long)bh*S_LEN + i];
  const float nfv = nf_arr[(long)bh*S_LEN + i];
  const float inv = 1.f / (fmaxf(fabsf(rsv), nfv) + 1e-6f);
  xv[0]*=inv; xv[1]*=inv; xv[2]*=inv; xv[3]*=inv;
  float sum = xv[0]+xv[1]+xv[2]+xv[3];
  float sq  = xv[0]*xv[0]+xv[1]*xv[1]+xv[2]*xv[2]+xv[3]*xv[3];
  for (int mk = 1; mk < 64; mk <<= 1) {
    sum += __shfl_xor(sum, mk);
    sq  += __shfl_xor(sq,  mk);
  }
  const float mean = sum * (1.f/256.f);
  const float var  = sq * (1.f/256.f) - mean*mean;
  const float rstd = rsqrtf(var + 1e-5f);
  f32x4 sc = *(const f32x4*)(lns + h*DHD + lane*4);
  f32x4 o;
  o[0]=(xv[0]-mean)*rstd*sc[0]; o[1]=(xv[1]-mean)*rstd*sc[1];
  o[2]=(xv[2]-mean)*rstd*sc[2]; o[3]=(xv[3]-mean)*rstd*sc[3];
  *(f32x4*)(outp + roff + lane*4) = o;
}

extern "C" void kernel_launch(void* const* d_in, const int* in_sizes, int n_in,
                              void* d_out, int out_size, void* d_ws, size_t ws_size,
                              hipStream_t stream) {
  const float* q   = (const float*)d_in[0];
  const float* k   = (const float*)d_in[1];
  const float* v   = (const float*)d_in[2];
  const float* wi  = (const float*)d_in[3];
  const float* bi  = (const float*)d_in[4];
  const float* wf  = (const float*)d_in[5];
  const float* bf_ = (const float*)d_in[6];
  const float* lns = (const float*)d_in[7];
  float* outp = (float*)d_out;

  char* ws = (char*)d_ws;
  const long nelem = (long)BH_CNT * S_LEN * DHD;      // 4,194,304
  short* Kg  = (short*)ws;
  short* Vg  = Kg + nelem;
  float* igA = (float*)(ws + 2*nelem*sizeof(short));
  float* fgA = igA + (long)BATCH*S_LEN*NHEAD;
  float* aA  = fgA + (long)BATCH*S_LEN*NHEAD;
  float* mA  = aA + (long)BH_CNT*S_LEN;
  float* nfA = mA + (long)BH_CNT*S_LEN;
  float* rsA = nfA + (long)BH_CNT*S_LEN;

  // zero accumulators: gates, output, rowsums
  hipMemsetAsync(igA, 0, 2 * (size_t)BATCH*S_LEN*NHEAD * sizeof(float), stream);
  hipMemsetAsync(outp, 0, (size_t)out_size * sizeof(float), stream);
  hipMemsetAsync(rsA, 0, (size_t)BH_CNT * S_LEN * sizeof(float), stream);

  prep_kernel<<<6144, 256, 0, stream>>>(q, k, v, wi, wf, Kg, Vg, igA, fgA);
  scan_kernel<<<BH_CNT, 256, 0, stream>>>(igA, fgA, bi, bf_, aA, mA, nfA);
  mlstm_partial_kernel<<<8*80, 256, 0, stream>>>(q, Kg, Vg, aA, mA, outp, rsA);
  finalize_kernel<<<BATCH*S_LEN, 256, 0, stream>>>(outp, rsA, nfA, lns);
}

// Round 11
// 170.169 us; speedup vs baseline: 1.3155x; 1.3155x over previous
//
#include <hip/hip_runtime.h>
#include <hip/hip_bf16.h>

// mLSTM parallel-stabilized cell, MI355X (gfx950).
// B=2, S=2048, H=1024, NH=4, DH=256.
// Identity: max_log_D[i] = cs[i] + m[i], m[i] = prefixmax(ig[j]-cs[j]);
// D[i][j] = exp(a[j]-m[i]), a[j] = ig[j]-cs[j], exponent always <= 0.
// R11: main = R9 per-period machinery VERBATIM (dbuf, vmcnt(16), kp-parity,
// Ols combine) but (bh,it) split into 2 half-key blocks (grid 504, largest-
// first) + R10's proven atomic epilogue + finalize. Prep: v-transpose family
// vectorized (f32x4 loads, 512 blocks), byte-identical Vg output.

#define S_LEN 2048
#define DHD   256
#define NHEAD 4
#define BATCH 2
#define HID   1024
#define BH_CNT (BATCH*NHEAD)

typedef __attribute__((ext_vector_type(8))) short bf16x8;
typedef __attribute__((ext_vector_type(4))) short short4v;
typedef __attribute__((ext_vector_type(4))) float f32x4;

static __device__ __forceinline__ short f2b(float f) {
  __hip_bfloat16 h = __float2bfloat16(f);
  return *reinterpret_cast<short*>(&h);
}

static __device__ __forceinline__ bf16x8 pack8(f32x4 a, f32x4 b) {
  bf16x8 o;
  o[0]=f2b(a[0]); o[1]=f2b(a[1]); o[2]=f2b(a[2]); o[3]=f2b(a[3]);
  o[4]=f2b(b[0]); o[5]=f2b(b[1]); o[6]=f2b(b[2]); o[7]=f2b(b[3]);
  return o;
}

// async global->LDS DMA, 16B/lane. ldsdst wave-uniform; lane l -> dst + l*16B.
static __device__ __forceinline__ void gload16(const void* src, void* ldsdst) {
  __builtin_amdgcn_global_load_lds(
      (const __attribute__((address_space(1))) void*)src,
      (__attribute__((address_space(3))) void*)ldsdst, 16, 0, 0);
}

// ---- kernel 1 (prep): grid 2560 x 256.
// bx <  2048 : merged gates (q+k+v parts, 2 rows) + k cast->Kg (swizzled)
// bx <  2560 : v transpose->Vg (swizzled), VECTORIZED 32x256 tiles
// Kg tile [bh][jt][32x256]: (r,d) at r*256 + (d ^ ((r&7)<<3)).
// Vg tile [bh][jt][256x32]: (d,j) at d*32 + (j ^ (((d>>1)&3)<<3)).
__global__ __launch_bounds__(256) void prep_kernel(
    const float* __restrict__ q, const float* __restrict__ k, const float* __restrict__ v,
    const float* __restrict__ wi, const float* __restrict__ wf,
    short* __restrict__ Kg, short* __restrict__ Vg,
    float* __restrict__ igA, float* __restrict__ fgA) {
  __shared__ short vt2[32][264];
  const int bx = blockIdx.x, t = threadIdx.x;
  if (bx < 2048) {
    const int g_row = bx * 2 + (t >> 7);
    const int col = (t & 127) * 8;
    const long off = (long)g_row*HID + col;
    const f32x4 xq0 = *(const f32x4*)(q + off);
    const f32x4 xq1 = *(const f32x4*)(q + off + 4);
    const f32x4 xk0 = *(const f32x4*)(k + off);
    const f32x4 xk1 = *(const f32x4*)(k + off + 4);
    const f32x4 xv0 = *(const f32x4*)(v + off);
    const f32x4 xv1 = *(const f32x4*)(v + off + 4);
    f32x4 ai = {0.f,0.f,0.f,0.f}, af = {0.f,0.f,0.f,0.f};
#pragma unroll
    for (int j = 0; j < 4; j++) {
      ai += xq0[j] * *(const f32x4*)(wi + (long)(col + j)*4);
      af += xq0[j] * *(const f32x4*)(wf + (long)(col + j)*4);
      ai += xq1[j] * *(const f32x4*)(wi + (long)(col + 4 + j)*4);
      af += xq1[j] * *(const f32x4*)(wf + (long)(col + 4 + j)*4);
      ai += xk0[j] * *(const f32x4*)(wi + (long)(HID + col + j)*4);
      af += xk0[j] * *(const f32x4*)(wf + (long)(HID + col + j)*4);
      ai += xk1[j] * *(const f32x4*)(wi + (long)(HID + col + 4 + j)*4);
      af += xk1[j] * *(const f32x4*)(wf + (long)(HID + col + 4 + j)*4);
      ai += xv0[j] * *(const f32x4*)(wi + (long)(2*HID + col + j)*4);
      af += xv0[j] * *(const f32x4*)(wf + (long)(2*HID + col + j)*4);
      ai += xv1[j] * *(const f32x4*)(wi + (long)(2*HID + col + 4 + j)*4);
      af += xv1[j] * *(const f32x4*)(wf + (long)(2*HID + col + 4 + j)*4);
    }
    {
      bf16x8 o = pack8(xk0, xk1);
      const int b = g_row >> 11, s = g_row & (S_LEN-1);
      const int hh = col >> 8, d = col & 255;
      const int bh = b*NHEAD + hh, jt = s >> 5, rr = s & 31;
      *(bf16x8*)(Kg + ((long)bh*64 + jt)*8192 + rr*256 + (d ^ ((rr & 7) << 3))) = o;
    }
    for (int mk = 32; mk >= 1; mk >>= 1) {
#pragma unroll
      for (int e = 0; e < 4; e++) {
        ai[e] += __shfl_xor(ai[e], mk);
        af[e] += __shfl_xor(af[e], mk);
      }
    }
    if ((t & 63) == 0) {
#pragma unroll
      for (int e = 0; e < 4; e++) {
        unsafeAtomicAdd(&igA[(long)g_row*NHEAD + e], ai[e]);
        unsafeAtomicAdd(&fgA[(long)g_row*NHEAD + e], af[e]);
      }
    }
  } else {
    // ---- vectorized v transpose -> Vg (swizzled tiles) ----
    const int t2 = bx - 2048;              // 0..511
    const int jt = t2 & 63, bhv = t2 >> 6;
    const int b = bhv >> 2, hh = bhv & 3;
    const int j0 = jt * 32;
    const int r0 = t >> 3, c0 = (t & 7) * 32;
    const float* vsrc = v + ((long)(b*S_LEN + j0 + r0))*HID + hh*DHD + c0;
#pragma unroll
    for (int i = 0; i < 4; i++) {
      f32x4 a  = *(const f32x4*)(vsrc + i*8);
      f32x4 bb = *(const f32x4*)(vsrc + i*8 + 4);
      *(bf16x8*)&vt2[r0][c0 + i*8] = pack8(a, bb);
    }
    __syncthreads();
    const long base = ((long)bhv*64 + jt) * 8192;
    const int j = t & 31, dg = t >> 5;
#pragma unroll
    for (int dd = 0; dd < 32; dd++) {
      const int d = dg*32 + dd;
      Vg[base + (long)d*32 + (j ^ (((d >> 1) & 3) << 3))] = vt2[j][d];
    }
  }
}

// ---- kernel 2: per-(b,h) scan (verbatim R9) ----
__global__ void scan_kernel(const float* __restrict__ ig, const float* __restrict__ fg,
                            const float* __restrict__ bi, const float* __restrict__ bf_,
                            float* __restrict__ a_out, float* __restrict__ m_out,
                            float* __restrict__ nf_out) {
  int bh = blockIdx.x, b = bh >> 2, h = bh & 3;
  int t = threadIdx.x;
  __shared__ float tot[256];
  long gbase = (long)b * S_LEN;
  const float biv = bi[h], bfv = bf_[h];
  float ls[8];
  float run = 0.f;
  for (int e = 0; e < 8; e++) {
    int s = t*8 + e;
    float x = fg[(gbase + s)*NHEAD + h] + bfv;
    float l = fminf(x, 0.f) - log1pf(expf(-fabsf(x)));  // stable log_sigmoid
    run += l; ls[e] = run;
  }
  tot[t] = run;
  __syncthreads();
  for (int off = 1; off < 256; off <<= 1) {
    float x = tot[t];
    if (t >= off) x += tot[t - off];
    __syncthreads();
    tot[t] = x;
    __syncthreads();
  }
  float offc = (t == 0) ? 0.f : tot[t-1];
  __syncthreads();
  float av[8], am[8], csv[8];
  float runm = -1e30f;
  for (int e = 0; e < 8; e++) {
    int s = t*8 + e;
    float cs = ls[e] + offc;
    csv[e] = cs;
    float a = (ig[(gbase + s)*NHEAD + h] + biv) - cs;
    av[e] = a;
    runm = fmaxf(runm, a);
    am[e] = runm;
  }
  tot[t] = runm;
  __syncthreads();
  for (int off = 1; off < 256; off <<= 1) {
    float x = tot[t];
    if (t >= off) x = fmaxf(x, tot[t - off]);
    __syncthreads();
    tot[t] = x;
    __syncthreads();
  }
  float offm = (t == 0) ? -1e30f : tot[t-1];
  long obase = (long)bh * S_LEN;
  for (int e = 0; e < 8; e++) {
    int s = t*8 + e;
    float mm = fmaxf(am[e], offm);
    a_out[obase + s]  = av[e];
    m_out[obase + s]  = mm;
    nf_out[obase + s] = expf(-(csv[e] + mm));
  }
}

// ---- kernel 3: main partial. 504 blocks = (bh, it, key-half), largest-first.
// R9 per-period machinery verbatim; epilogue = kp-combine + atomic O/rowsum.
__global__ __launch_bounds__(256, 1) void mlstm_partial_kernel(
    const float* __restrict__ q, const short* __restrict__ Kg, const short* __restrict__ Vg,
    const float* __restrict__ a_arr, const float* __restrict__ m_arr,
    float* __restrict__ outp, float* __restrict__ rsacc) {
  __shared__ alignas(16) short Kst[2][2][8192];   // [dbuf][parity][32k x 256d swz]
  __shared__ alignas(16) short Vst[2][2][8192];   // [dbuf][parity][256d x 32j swz]
  __shared__ alignas(16) short plds[4][16*36];
  const int w = threadIdx.x >> 6, lane = threadIdx.x & 63;
  const int lr = lane & 15, g = lane >> 4;
  const int rg2 = w >> 1, kp = w & 1;
  const int bh = blockIdx.x & 7;
  const int idx = blockIdx.x >> 3;        // 0..62, largest-first
  int it, half;
  if (idx < 62) { it = 31 - (idx >> 1); half = idx & 1; }
  else          { it = 0;  half = 0; }
  const int P = it + 1, np0 = (P + 1) >> 1;
  const int p_begin = half ? np0 : 0;
  const int p_end   = half ? P : np0;
  const int b = bh >> 2, h = bh & 3;
  const int R0 = it*64 + rg2*32;          // wave's first global row
  const long arow = (long)bh * S_LEN;
  const int ntw = it*2 + rg2 + 1;         // wave computes jtc < ntw (parity kp)
  const f32x4 zz = {0.f,0.f,0.f,0.f};
  const int sw = (lr & 7) << 3;

  // Q fragments for the wave's 32 rows, cast inline from fp32 source
  bf16x8 qfa[8], qfb[8];
  const float* qsrc = q + ((long)(b*S_LEN + R0 + lr))*HID + h*DHD + g*8;
#pragma unroll
  for (int c8 = 0; c8 < 8; c8++) {
    f32x4 u0 = *(const f32x4*)(qsrc + c8*32);
    f32x4 u1 = *(const f32x4*)(qsrc + c8*32 + 4);
    f32x4 w0 = *(const f32x4*)(qsrc + 16*HID + c8*32);
    f32x4 w1 = *(const f32x4*)(qsrc + 16*HID + c8*32 + 4);
    qfa[c8] = pack8(u0, u1);
    qfb[c8] = pack8(w0, w1);
  }
  float ma[4], mb[4];
#pragma unroll
  for (int r = 0; r < 4; r++) {
    ma[r] = m_arr[arow + R0 + g*4 + r];
    mb[r] = m_arr[arow + R0 + 16 + g*4 + r];
  }

  f32x4 oa[16], ob[16];
#pragma unroll
  for (int t = 0; t < 16; t++) { oa[t] = zz; ob[t] = zz; }
  float rs_a[4] = {0,0,0,0}, rs_b[4] = {0,0,0,0};
  short* myp = plds[w];

  // wave w stages one 16KB tile-buffer per period: w<2 -> K parity w, else V.
  auto STAGE = [&](int pb, int p) {
    const int jts = 2*p + (w & 1);
    short* dst = (w < 2) ? &Kst[pb][w & 1][0] : &Vst[pb][w & 1][0];
    const short* src = ((w < 2) ? Kg : Vg) + ((long)bh*64 + jts)*8192 + lane*8;
#pragma unroll
    for (int u = 0; u < 16; u++)
      gload16(src + u*512, dst + u*512);
  };

  float aC0, aC1, aN0 = 0.f, aN1 = 0.f;
  STAGE(0, p_begin);
  { const int j0 = (2*p_begin + kp)*32;
    aC0 = a_arr[arow + j0 + lr]; aC1 = a_arr[arow + j0 + 16 + lr]; }

  for (int p = p_begin; p < p_end; ++p) {
    const int pb = (p - p_begin) & 1;
    if (p + 1 < p_end) {
      STAGE(pb ^ 1, p + 1);
      { const int j0 = (2*(p+1) + kp)*32;
        aN0 = a_arr[arow + j0 + lr]; aN1 = a_arr[arow + j0 + 16 + lr]; }
      asm volatile("s_waitcnt vmcnt(16)" ::: "memory");  // own 16 DMA of tile p done
    } else {
      asm volatile("s_waitcnt vmcnt(0)" ::: "memory");
    }
    __builtin_amdgcn_s_barrier();

    const int jtc = 2*p + kp;
    if (jtc < ntw) {
      const int j0 = jtc*32;
      const short* Kt = &Kst[pb][kp][0];
      const short* Vt = &Vst[pb][kp][0];
      f32x4 s0a = zz, s1a = zz, s0b = zz, s1b = zz;
      __builtin_amdgcn_s_setprio(1);
#pragma unroll
      for (int c8 = 0; c8 < 8; c8++) {
        const int ko = lr*256 + ((c8*32 + g*8) ^ sw);
        bf16x8 k0 = *(const bf16x8*)&Kt[ko];
        bf16x8 k1 = *(const bf16x8*)&Kt[ko + 4096];
        s0a = __builtin_amdgcn_mfma_f32_16x16x32_bf16(qfa[c8], k0, s0a, 0, 0, 0);
        s0b = __builtin_amdgcn_mfma_f32_16x16x32_bf16(qfb[c8], k0, s0b, 0, 0, 0);
        s1a = __builtin_amdgcn_mfma_f32_16x16x32_bf16(qfa[c8], k1, s1a, 0, 0, 0);
        s1b = __builtin_amdgcn_mfma_f32_16x16x32_bf16(qfb[c8], k1, s1b, 0, 0, 0);
      }
      __builtin_amdgcn_s_setprio(0);
      // ---- group a: P + re-fragment ----
      bf16x8 pa_a, pa_b;
      {
        const bool needmask = (j0 + 31 > R0);
#pragma unroll
        for (int r = 0; r < 4; r++) {
          const int i = R0 + g*4 + r;
          float p0 = s0a[r] * 0.0625f * __expf(aC0 - ma[r]);
          float p1 = s1a[r] * 0.0625f * __expf(aC1 - ma[r]);
          if (needmask) {
            if (j0 + lr > i)      p0 = 0.f;
            if (j0 + 16 + lr > i) p1 = 0.f;
          }
          rs_a[r] += p0 + p1;
          myp[(g*4 + r)*36 + lr]      = f2b(p0);
          myp[(g*4 + r)*36 + 16 + lr] = f2b(p1);
        }
        const short* rp = myp + lr*36 + g*8;
        short4v plo = *(const short4v*)rp;
        short4v phi = *(const short4v*)(rp + 4);
        pa_a = bf16x8{plo[0],plo[1],plo[2],plo[3],phi[0],phi[1],phi[2],phi[3]};
      }
      // ---- group b ----
      {
        const bool needmask = (j0 + 31 > R0 + 16);
#pragma unroll
        for (int r = 0; r < 4; r++) {
          const int i = R0 + 16 + g*4 + r;
          float p0 = s0b[r] * 0.0625f * __expf(aC0 - mb[r]);
          float p1 = s1b[r] * 0.0625f * __expf(aC1 - mb[r]);
          if (needmask) {
            if (j0 + lr > i)      p0 = 0.f;
            if (j0 + 16 + lr > i) p1 = 0.f;
          }
          rs_b[r] += p0 + p1;
          myp[(g*4 + r)*36 + lr]      = f2b(p0);
          myp[(g*4 + r)*36 + 16 + lr] = f2b(p1);
        }
        const short* rp = myp + lr*36 + g*8;
        short4v plo = *(const short4v*)rp;
        short4v phi = *(const short4v*)(rp + 4);
        pa_b = bf16x8{plo[0],plo[1],plo[2],plo[3],phi[0],phi[1],phi[2],phi[3]};
      }
      // ---- PV: read each V fragment ONCE, feed both row groups ----
      __builtin_amdgcn_s_setprio(1);
#pragma unroll
      for (int t = 0; t < 16; t++) {
        const int d = t*16 + lr;
        const int vo = d*32 + ((g*8) ^ (((d >> 1) & 3) << 3));
        bf16x8 vf = *(const bf16x8*)&Vt[vo];
        oa[t] = __builtin_amdgcn_mfma_f32_16x16x32_bf16(pa_a, vf, oa[t], 0, 0, 0);
        ob[t] = __builtin_amdgcn_mfma_f32_16x16x32_bf16(pa_b, vf, ob[t], 0, 0, 0);
      }
      __builtin_amdgcn_s_setprio(0);
    }
    __builtin_amdgcn_s_barrier();
    if (p + 1 < p_end) { aC0 = aN0; aC1 = aN1; }
  }

  // ---- rowsum reduce over the 16 key-columns ----
#pragma unroll
  for (int r = 0; r < 4; r++)
    for (int mk = 1; mk < 16; mk <<= 1) {
      rs_a[r] += __shfl_xor(rs_a[r], mk);
      rs_b[r] += __shfl_xor(rs_b[r], mk);
    }

  // ---- combine key-parities via LDS (kp=1 writes, kp=0 adds + atomics) ----
  float* Ols = (float*)&Kst[0][0][0];   // 64 rows x 256 d fp32 = 64 KB
  float* rsl = (float*)&Vst[0][0][0];   // 64 rowsums
  __syncthreads();
  if (kp == 1) {
#pragma unroll
    for (int r = 0; r < 4; r++) {
      const int rla = rg2*32 + g*4 + r, rlb = rla + 16;
#pragma unroll
      for (int t = 0; t < 16; t++) {
        Ols[(long)rla*256 + t*16 + lr] = oa[t][r];
        Ols[(long)rlb*256 + t*16 + lr] = ob[t][r];
      }
      if (lr == 0) { rsl[rla] = rs_a[r]; rsl[rlb] = rs_b[r]; }
    }
  }
  __syncthreads();
  if (kp == 0) {
    for (int grp = 0; grp < 2; grp++) {
      f32x4* acc = grp ? ob : oa;
      float* rsv = grp ? rs_b : rs_a;
#pragma unroll
      for (int r = 0; r < 4; r++) {
        const int rl = rg2*32 + grp*16 + g*4 + r;
        const int i = R0 + grp*16 + g*4 + r;
        float* orow = outp + ((long)(b*S_LEN + i))*HID + h*DHD + lr;
#pragma unroll
        for (int t = 0; t < 16; t++)
          unsafeAtomicAdd(orow + t*16, acc[t][r] + Ols[(long)rl*256 + t*16 + lr]);
        if (lr == 0)
          unsafeAtomicAdd(&rsacc[arow + i], rsv[r] + rsl[rl]);
      }
    }
  }
}

// ---- kernel 4: finalize — normalizer + per-head LayerNorm (verbatim R10) ----
__global__ __launch_bounds__(256) void finalize_kernel(
    float* __restrict__ outp, const float* __restrict__ rsacc,
    const float* __restrict__ nf_arr, const float* __restrict__ lns) {
  const int bi = blockIdx.x;                  // b*S + i
  const int h = threadIdx.x >> 6, lane = threadIdx.x & 63;
  const int b = bi >> 11, i = bi & (S_LEN-1);
  const int bh = b*NHEAD + h;
  const long roff = (long)bi * HID + (long)h*DHD;
  f32x4 xv = *(const f32x4*)(outp + roff + lane*4);
  const float rsv = rsacc[(long)bh*S_LEN + i];
  const float nfv = nf_arr[(long)bh*S_LEN + i];
  const float inv = 1.f / (fmaxf(fabsf(rsv), nfv) + 1e-6f);
  xv[0]*=inv; xv[1]*=inv; xv[2]*=inv; xv[3]*=inv;
  float sum = xv[0]+xv[1]+xv[2]+xv[3];
  float sq  = xv[0]*xv[0]+xv[1]*xv[1]+xv[2]*xv[2]+xv[3]*xv[3];
  for (int mk = 1; mk < 64; mk <<= 1) {
    sum += __shfl_xor(sum, mk);
    sq  += __shfl_xor(sq,  mk);
  }
  const float mean = sum * (1.f/256.f);
  const float var  = sq * (1.f/256.f) - mean*mean;
  const float rstd = rsqrtf(var + 1e-5f);
  f32x4 sc = *(const f32x4*)(lns + h*DHD + lane*4);
  f32x4 o;
  o[0]=(xv[0]-mean)*rstd*sc[0]; o[1]=(xv[1]-mean)*rstd*sc[1];
  o[2]=(xv[2]-mean)*rstd*sc[2]; o[3]=(xv[3]-mean)*rstd*sc[3];
  *(f32x4*)(outp + roff + lane*4) = o;
}

extern "C" void kernel_launch(void* const* d_in, const int* in_sizes, int n_in,
                              void* d_out, int out_size, void* d_ws, size_t ws_size,
                              hipStream_t stream) {
  const float* q   = (const float*)d_in[0];
  const float* k   = (const float*)d_in[1];
  const float* v   = (const float*)d_in[2];
  const float* wi  = (const float*)d_in[3];
  const float* bi  = (const float*)d_in[4];
  const float* wf  = (const float*)d_in[5];
  const float* bf_ = (const float*)d_in[6];
  const float* lns = (const float*)d_in[7];
  float* outp = (float*)d_out;

  char* ws = (char*)d_ws;
  const long nelem = (long)BH_CNT * S_LEN * DHD;      // 4,194,304
  short* Kg  = (short*)ws;
  short* Vg  = Kg + nelem;
  float* igA = (float*)(ws + 2*nelem*sizeof(short));
  float* fgA = igA + (long)BATCH*S_LEN*NHEAD;
  float* aA  = fgA + (long)BATCH*S_LEN*NHEAD;
  float* mA  = aA + (long)BH_CNT*S_LEN;
  float* nfA = mA + (long)BH_CNT*S_LEN;
  float* rsA = nfA + (long)BH_CNT*S_LEN;

  // zero accumulators: gates, output, rowsums
  hipMemsetAsync(igA, 0, 2 * (size_t)BATCH*S_LEN*NHEAD * sizeof(float), stream);
  hipMemsetAsync(outp, 0, (size_t)out_size * sizeof(float), stream);
  hipMemsetAsync(rsA, 0, (size_t)BH_CNT * S_LEN * sizeof(float), stream);

  prep_kernel<<<2560, 256, 0, stream>>>(q, k, v, wi, wf, Kg, Vg, igA, fgA);
  scan_kernel<<<BH_CNT, 256, 0, stream>>>(igA, fgA, bi, bf_, aA, mA, nfA);
  mlstm_partial_kernel<<<8*63, 256, 0, stream>>>(q, Kg, Vg, aA, mA, outp, rsA);
  finalize_kernel<<<BATCH*S_LEN, 256, 0, stream>>>(outp, rsA, nfA, lns);
}

// Round 12
// 165.907 us; speedup vs baseline: 1.3493x; 1.0257x over previous
//
#include <hip/hip_runtime.h>
#include <hip/hip_bf16.h>

// mLSTM parallel-stabilized cell, MI355X (gfx950).
// B=2, S=2048, H=1024, NH=4, DH=256.
// Identity: max_log_D[i] = cs[i] + m[i], m[i] = prefixmax(ig[j]-cs[j]);
// D[i][j] = exp(a[j]-m[i]), a[j] = ig[j]-cs[j], exponent always <= 0.
// R12: R9 main (256 blocks, dbuf, fused LN epilogue) with 3 surgical fixes:
// (1) vmcnt 16->18 (FIFO off-by-2: old count stalled on 2 just-issued DMAs
//     every period) + a-loads hoisted before STAGE;
// (2) QK MFMA chains split 8-deep -> 2x4-deep (halves exposed MFMA latency);
// (3) separate P-bounce LDS buffers for row-groups a/b (kills WAR serializer).
// Prep/scan = R11 verbatim (vectorized v-transpose, merged gates).

#define S_LEN 2048
#define DHD   256
#define NHEAD 4
#define BATCH 2
#define HID   1024
#define BH_CNT (BATCH*NHEAD)

typedef __attribute__((ext_vector_type(8))) short bf16x8;
typedef __attribute__((ext_vector_type(4))) short short4v;
typedef __attribute__((ext_vector_type(4))) float f32x4;

static __device__ __forceinline__ short f2b(float f) {
  __hip_bfloat16 h = __float2bfloat16(f);
  return *reinterpret_cast<short*>(&h);
}

static __device__ __forceinline__ bf16x8 pack8(f32x4 a, f32x4 b) {
  bf16x8 o;
  o[0]=f2b(a[0]); o[1]=f2b(a[1]); o[2]=f2b(a[2]); o[3]=f2b(a[3]);
  o[4]=f2b(b[0]); o[5]=f2b(b[1]); o[6]=f2b(b[2]); o[7]=f2b(b[3]);
  return o;
}

// async global->LDS DMA, 16B/lane. ldsdst wave-uniform; lane l -> dst + l*16B.
static __device__ __forceinline__ void gload16(const void* src, void* ldsdst) {
  __builtin_amdgcn_global_load_lds(
      (const __attribute__((address_space(1))) void*)src,
      (__attribute__((address_space(3))) void*)ldsdst, 16, 0, 0);
}

// ---- kernel 1 (prep): grid 2560 x 256. (verbatim R11)
// bx <  2048 : merged gates (q+k+v parts, 2 rows) + k cast->Kg (swizzled)
// bx <  2560 : v transpose->Vg (swizzled), VECTORIZED 32x256 tiles
// Kg tile [bh][jt][32x256]: (r,d) at r*256 + (d ^ ((r&7)<<3)).
// Vg tile [bh][jt][256x32]: (d,j) at d*32 + (j ^ (((d>>1)&3)<<3)).
__global__ __launch_bounds__(256) void prep_kernel(
    const float* __restrict__ q, const float* __restrict__ k, const float* __restrict__ v,
    const float* __restrict__ wi, const float* __restrict__ wf,
    short* __restrict__ Kg, short* __restrict__ Vg,
    float* __restrict__ igA, float* __restrict__ fgA) {
  __shared__ short vt2[32][264];
  const int bx = blockIdx.x, t = threadIdx.x;
  if (bx < 2048) {
    const int g_row = bx * 2 + (t >> 7);
    const int col = (t & 127) * 8;
    const long off = (long)g_row*HID + col;
    const f32x4 xq0 = *(const f32x4*)(q + off);
    const f32x4 xq1 = *(const f32x4*)(q + off + 4);
    const f32x4 xk0 = *(const f32x4*)(k + off);
    const f32x4 xk1 = *(const f32x4*)(k + off + 4);
    const f32x4 xv0 = *(const f32x4*)(v + off);
    const f32x4 xv1 = *(const f32x4*)(v + off + 4);
    f32x4 ai = {0.f,0.f,0.f,0.f}, af = {0.f,0.f,0.f,0.f};
#pragma unroll
    for (int j = 0; j < 4; j++) {
      ai += xq0[j] * *(const f32x4*)(wi + (long)(col + j)*4);
      af += xq0[j] * *(const f32x4*)(wf + (long)(col + j)*4);
      ai += xq1[j] * *(const f32x4*)(wi + (long)(col + 4 + j)*4);
      af += xq1[j] * *(const f32x4*)(wf + (long)(col + 4 + j)*4);
      ai += xk0[j] * *(const f32x4*)(wi + (long)(HID + col + j)*4);
      af += xk0[j] * *(const f32x4*)(wf + (long)(HID + col + j)*4);
      ai += xk1[j] * *(const f32x4*)(wi + (long)(HID + col + 4 + j)*4);
      af += xk1[j] * *(const f32x4*)(wf + (long)(HID + col + 4 + j)*4);
      ai += xv0[j] * *(const f32x4*)(wi + (long)(2*HID + col + j)*4);
      af += xv0[j] * *(const f32x4*)(wf + (long)(2*HID + col + j)*4);
      ai += xv1[j] * *(const f32x4*)(wi + (long)(2*HID + col + 4 + j)*4);
      af += xv1[j] * *(const f32x4*)(wf + (long)(2*HID + col + 4 + j)*4);
    }
    {
      bf16x8 o = pack8(xk0, xk1);
      const int b = g_row >> 11, s = g_row & (S_LEN-1);
      const int hh = col >> 8, d = col & 255;
      const int bh = b*NHEAD + hh, jt = s >> 5, rr = s & 31;
      *(bf16x8*)(Kg + ((long)bh*64 + jt)*8192 + rr*256 + (d ^ ((rr & 7) << 3))) = o;
    }
    for (int mk = 32; mk >= 1; mk >>= 1) {
#pragma unroll
      for (int e = 0; e < 4; e++) {
        ai[e] += __shfl_xor(ai[e], mk);
        af[e] += __shfl_xor(af[e], mk);
      }
    }
    if ((t & 63) == 0) {
#pragma unroll
      for (int e = 0; e < 4; e++) {
        unsafeAtomicAdd(&igA[(long)g_row*NHEAD + e], ai[e]);
        unsafeAtomicAdd(&fgA[(long)g_row*NHEAD + e], af[e]);
      }
    }
  } else {
    // ---- vectorized v transpose -> Vg (swizzled tiles) ----
    const int t2 = bx - 2048;              // 0..511
    const int jt = t2 & 63, bhv = t2 >> 6;
    const int b = bhv >> 2, hh = bhv & 3;
    const int j0 = jt * 32;
    const int r0 = t >> 3, c0 = (t & 7) * 32;
    const float* vsrc = v + ((long)(b*S_LEN + j0 + r0))*HID + hh*DHD + c0;
#pragma unroll
    for (int i = 0; i < 4; i++) {
      f32x4 a  = *(const f32x4*)(vsrc + i*8);
      f32x4 bb = *(const f32x4*)(vsrc + i*8 + 4);
      *(bf16x8*)&vt2[r0][c0 + i*8] = pack8(a, bb);
    }
    __syncthreads();
    const long base = ((long)bhv*64 + jt) * 8192;
    const int j = t & 31, dg = t >> 5;
#pragma unroll
    for (int dd = 0; dd < 32; dd++) {
      const int d = dg*32 + dd;
      Vg[base + (long)d*32 + (j ^ (((d >> 1) & 3) << 3))] = vt2[j][d];
    }
  }
}

// ---- kernel 2: per-(b,h) scan (verbatim R9) ----
__global__ void scan_kernel(const float* __restrict__ ig, const float* __restrict__ fg,
                            const float* __restrict__ bi, const float* __restrict__ bf_,
                            float* __restrict__ a_out, float* __restrict__ m_out,
                            float* __restrict__ nf_out) {
  int bh = blockIdx.x, b = bh >> 2, h = bh & 3;
  int t = threadIdx.x;
  __shared__ float tot[256];
  long gbase = (long)b * S_LEN;
  const float biv = bi[h], bfv = bf_[h];
  float ls[8];
  float run = 0.f;
  for (int e = 0; e < 8; e++) {
    int s = t*8 + e;
    float x = fg[(gbase + s)*NHEAD + h] + bfv;
    float l = fminf(x, 0.f) - log1pf(expf(-fabsf(x)));  // stable log_sigmoid
    run += l; ls[e] = run;
  }
  tot[t] = run;
  __syncthreads();
  for (int off = 1; off < 256; off <<= 1) {
    float x = tot[t];
    if (t >= off) x += tot[t - off];
    __syncthreads();
    tot[t] = x;
    __syncthreads();
  }
  float offc = (t == 0) ? 0.f : tot[t-1];
  __syncthreads();
  float av[8], am[8], csv[8];
  float runm = -1e30f;
  for (int e = 0; e < 8; e++) {
    int s = t*8 + e;
    float cs = ls[e] + offc;
    csv[e] = cs;
    float a = (ig[(gbase + s)*NHEAD + h] + biv) - cs;
    av[e] = a;
    runm = fmaxf(runm, a);
    am[e] = runm;
  }
  tot[t] = runm;
  __syncthreads();
  for (int off = 1; off < 256; off <<= 1) {
    float x = tot[t];
    if (t >= off) x = fmaxf(x, tot[t - off]);
    __syncthreads();
    tot[t] = x;
    __syncthreads();
  }
  float offm = (t == 0) ? -1e30f : tot[t-1];
  long obase = (long)bh * S_LEN;
  for (int e = 0; e < 8; e++) {
    int s = t*8 + e;
    float mm = fmaxf(am[e], offm);
    a_out[obase + s]  = av[e];
    m_out[obase + s]  = mm;
    nf_out[obase + s] = expf(-(csv[e] + mm));
  }
}

// ---- kernel 3: main. 256 blocks = (bh, it). 4 waves = 2 rg2 x 2 kp. ----
// R9 machinery + vmcnt(18) fix + split QK chains + dual P-bounce buffers.
__global__ __launch_bounds__(256, 1) void mlstm_main_kernel(
    const float* __restrict__ q, const short* __restrict__ Kg, const short* __restrict__ Vg,
    const float* __restrict__ a_arr, const float* __restrict__ m_arr,
    const float* __restrict__ nf_arr, const float* __restrict__ lns,
    float* __restrict__ outp) {
  __shared__ alignas(16) short Kst[2][2][8192];   // [dbuf][parity][32k x 256d swz]
  __shared__ alignas(16) short Vst[2][2][8192];   // [dbuf][parity][256d x 32j swz]
  __shared__ alignas(16) short plds[8][16*36];    // dual P-bounce: [w]=grp a, [4+w]=grp b
  const int w = threadIdx.x >> 6, lane = threadIdx.x & 63;
  const int lr = lane & 15, g = lane >> 4;
  const int rg2 = w >> 1, kp = w & 1;
  const int bh = blockIdx.x & 7, it = blockIdx.x >> 3;
  const int b = bh >> 2, h = bh & 3;
  const int R0 = it*64 + rg2*32;          // wave's first global row
  const long arow = (long)bh * S_LEN;
  const int np = it + 1;                  // periods (2 tiles each)
  const int ntw = it*2 + rg2 + 1;         // wave computes jt < ntw (parity kp)
  const f32x4 zz = {0.f,0.f,0.f,0.f};
  const int sw = (lr & 7) << 3;

  // Q fragments for the wave's 32 rows, cast inline from fp32 source
  bf16x8 qfa[8], qfb[8];
  const float* qsrc = q + ((long)(b*S_LEN + R0 + lr))*HID + h*DHD + g*8;
#pragma unroll
  for (int c8 = 0; c8 < 8; c8++) {
    f32x4 u0 = *(const f32x4*)(qsrc + c8*32);
    f32x4 u1 = *(const f32x4*)(qsrc + c8*32 + 4);
    f32x4 w0 = *(const f32x4*)(qsrc + 16*HID + c8*32);
    f32x4 w1 = *(const f32x4*)(qsrc + 16*HID + c8*32 + 4);
    qfa[c8] = pack8(u0, u1);
    qfb[c8] = pack8(w0, w1);
  }
  float ma[4], mb[4];
#pragma unroll
  for (int r = 0; r < 4; r++) {
    ma[r] = m_arr[arow + R0 + g*4 + r];
    mb[r] = m_arr[arow + R0 + 16 + g*4 + r];
  }

  f32x4 oa[16], ob[16];
#pragma unroll
  for (int t = 0; t < 16; t++) { oa[t] = zz; ob[t] = zz; }
  float rs_a[4] = {0,0,0,0}, rs_b[4] = {0,0,0,0};
  short* myp_a = plds[w];
  short* myp_b = plds[4 + w];

  // wave w stages one 16KB tile-buffer per period: w<2 -> K parity w, else V.
  auto STAGE = [&](int pb, int p) {
    const int jts = 2*p + (w & 1);
    short* dst = (w < 2) ? &Kst[pb][w & 1][0] : &Vst[pb][w & 1][0];
    const short* src = ((w < 2) ? Kg : Vg) + ((long)bh*64 + jts)*8192 + lane*8;
#pragma unroll
    for (int u = 0; u < 16; u++)
      gload16(src + u*512, dst + u*512);
  };

  float aC0, aC1, aN0 = 0.f, aN1 = 0.f;
  STAGE(0, 0);
  { const int j0 = kp*32;
    aC0 = a_arr[arow + j0 + lr]; aC1 = a_arr[arow + j0 + 16 + lr]; }

  for (int p = 0; p < np; ++p) {
    const int pb = p & 1;
    if (p + 1 < np) {
      { const int j0 = (2*(p+1) + kp)*32;   // a-loads BEFORE stage
        aN0 = a_arr[arow + j0 + lr]; aN1 = a_arr[arow + j0 + 16 + lr]; }
      STAGE(pb ^ 1, p + 1);
      // vmcnt(18): complete tile p's 16 DMAs; leave tile p+1's 16 + 2 a-loads
      // in flight (correct under either load/STAGE compiler ordering).
      asm volatile("s_waitcnt vmcnt(18)" ::: "memory");
    } else {
      asm volatile("s_waitcnt vmcnt(0)" ::: "memory");
    }
    __builtin_amdgcn_s_barrier();

    const int jtc = 2*p + kp;
    if (jtc < ntw) {
      const int j0 = jtc*32;
      const short* Kt = &Kst[pb][kp][0];
      const short* Vt = &Vst[pb][kp][0];
      // split accumulator chains: 8 independent 4-deep MFMA chains
      f32x4 s0a0 = zz, s0a1 = zz, s1a0 = zz, s1a1 = zz;
      f32x4 s0b0 = zz, s0b1 = zz, s1b0 = zz, s1b1 = zz;
      __builtin_amdgcn_s_setprio(1);
#pragma unroll
      for (int c8 = 0; c8 < 8; c8++) {
        const int ko = lr*256 + ((c8*32 + g*8) ^ sw);
        bf16x8 k0 = *(const bf16x8*)&Kt[ko];
        bf16x8 k1 = *(const bf16x8*)&Kt[ko + 4096];
        if (c8 < 4) {
          s0a0 = __builtin_amdgcn_mfma_f32_16x16x32_bf16(qfa[c8], k0, s0a0, 0, 0, 0);
          s0b0 = __builtin_amdgcn_mfma_f32_16x16x32_bf16(qfb[c8], k0, s0b0, 0, 0, 0);
          s1a0 = __builtin_amdgcn_mfma_f32_16x16x32_bf16(qfa[c8], k1, s1a0, 0, 0, 0);
          s1b0 = __builtin_amdgcn_mfma_f32_16x16x32_bf16(qfb[c8], k1, s1b0, 0, 0, 0);
        } else {
          s0a1 = __builtin_amdgcn_mfma_f32_16x16x32_bf16(qfa[c8], k0, s0a1, 0, 0, 0);
          s0b1 = __builtin_amdgcn_mfma_f32_16x16x32_bf16(qfb[c8], k0, s0b1, 0, 0, 0);
          s1a1 = __builtin_amdgcn_mfma_f32_16x16x32_bf16(qfa[c8], k1, s1a1, 0, 0, 0);
          s1b1 = __builtin_amdgcn_mfma_f32_16x16x32_bf16(qfb[c8], k1, s1b1, 0, 0, 0);
        }
      }
      __builtin_amdgcn_s_setprio(0);
      const f32x4 s0a = s0a0 + s0a1, s1a = s1a0 + s1a1;
      const f32x4 s0b = s0b0 + s0b1, s1b = s1b0 + s1b1;
      // ---- group a: P + re-fragment (buffer A) ----
      bf16x8 pa_a, pa_b;
      {
        const bool needmask = (j0 + 31 > R0);
#pragma unroll
        for (int r = 0; r < 4; r++) {
          const int i = R0 + g*4 + r;
          float p0 = s0a[r] * 0.0625f * __expf(aC0 - ma[r]);
          float p1 = s1a[r] * 0.0625f * __expf(aC1 - ma[r]);
          if (needmask) {
            if (j0 + lr > i)      p0 = 0.f;
            if (j0 + 16 + lr > i) p1 = 0.f;
          }
          rs_a[r] += p0 + p1;
          myp_a[(g*4 + r)*36 + lr]      = f2b(p0);
          myp_a[(g*4 + r)*36 + 16 + lr] = f2b(p1);
        }
      }
      // ---- group b: P (buffer B; no wait on group a's reads) ----
      {
        const bool needmask = (j0 + 31 > R0 + 16);
#pragma unroll
        for (int r = 0; r < 4; r++) {
          const int i = R0 + 16 + g*4 + r;
          float p0 = s0b[r] * 0.0625f * __expf(aC0 - mb[r]);
          float p1 = s1b[r] * 0.0625f * __expf(aC1 - mb[r]);
          if (needmask) {
            if (j0 + lr > i)      p0 = 0.f;
            if (j0 + 16 + lr > i) p1 = 0.f;
          }
          rs_b[r] += p0 + p1;
          myp_b[(g*4 + r)*36 + lr]      = f2b(p0);
          myp_b[(g*4 + r)*36 + 16 + lr] = f2b(p1);
        }
      }
      {
        const short* rpa = myp_a + lr*36 + g*8;
        short4v plo = *(const short4v*)rpa;
        short4v phi = *(const short4v*)(rpa + 4);
        pa_a = bf16x8{plo[0],plo[1],plo[2],plo[3],phi[0],phi[1],phi[2],phi[3]};
        const short* rpb = myp_b + lr*36 + g*8;
        short4v qlo = *(const short4v*)rpb;
        short4v qhi = *(const short4v*)(rpb + 4);
        pa_b = bf16x8{qlo[0],qlo[1],qlo[2],qlo[3],qhi[0],qhi[1],qhi[2],qhi[3]};
      }
      // ---- PV: read each V fragment ONCE, feed both row groups ----
      __builtin_amdgcn_s_setprio(1);
#pragma unroll
      for (int t = 0; t < 16; t++) {
        const int d = t*16 + lr;
        const int vo = d*32 + ((g*8) ^ (((d >> 1) & 3) << 3));
        bf16x8 vf = *(const bf16x8*)&Vt[vo];
        oa[t] = __builtin_amdgcn_mfma_f32_16x16x32_bf16(pa_a, vf, oa[t], 0, 0, 0);
        ob[t] = __builtin_amdgcn_mfma_f32_16x16x32_bf16(pa_b, vf, ob[t], 0, 0, 0);
      }
      __builtin_amdgcn_s_setprio(0);
    }
    __builtin_amdgcn_s_barrier();
    if (p + 1 < np) { aC0 = aN0; aC1 = aN1; }
  }

  // ---- rowsum reduce over the 16 key-columns ----
#pragma unroll
  for (int r = 0; r < 4; r++)
    for (int mk = 1; mk < 16; mk <<= 1) {
      rs_a[r] += __shfl_xor(rs_a[r], mk);
      rs_b[r] += __shfl_xor(rs_b[r], mk);
    }

  // ---- combine key-parities via LDS (kp=1 writes, kp=0 reduces + LN) ----
  float* Ols = (float*)&Kst[0][0][0];   // 64 rows x 256 d fp32 = 64 KB
  float* rsl = (float*)&Vst[0][0][0];   // 64 rowsums
  __syncthreads();
  if (kp == 1) {
#pragma unroll
    for (int r = 0; r < 4; r++) {
      const int rla = rg2*32 + g*4 + r, rlb = rla + 16;
#pragma unroll
      for (int t = 0; t < 16; t++) {
        Ols[(long)rla*256 + t*16 + lr] = oa[t][r];
        Ols[(long)rlb*256 + t*16 + lr] = ob[t][r];
      }
      if (lr == 0) { rsl[rla] = rs_a[r]; rsl[rlb] = rs_b[r]; }
    }
  }
  __syncthreads();
  if (kp == 0) {
    float sc[16];
#pragma unroll
    for (int t = 0; t < 16; t++) sc[t] = lns[h*DHD + t*16 + lr];
    for (int grp = 0; grp < 2; grp++) {
      f32x4* acc = grp ? ob : oa;
      float* rsv = grp ? rs_b : rs_a;
#pragma unroll
      for (int r = 0; r < 4; r++) {
        const int rl = rg2*32 + grp*16 + g*4 + r;
        const int i = R0 + grp*16 + g*4 + r;
        const float rst = rsv[r] + rsl[rl];
        const float nfv = nf_arr[arow + i];
        const float inv = 1.f / (fmaxf(fabsf(rst), nfv) + 1e-6f);
        float sum = 0.f, sq = 0.f;
        float xv[16];
#pragma unroll
        for (int t = 0; t < 16; t++) {
          float x = (acc[t][r] + Ols[(long)rl*256 + t*16 + lr]) * inv;
          xv[t] = x; sum += x; sq += x*x;
        }
        for (int mk = 1; mk < 16; mk <<= 1) {
          sum += __shfl_xor(sum, mk);
          sq  += __shfl_xor(sq,  mk);
        }
        const float mean = sum * (1.f/256.f);
        const float var  = sq * (1.f/256.f) - mean*mean;
        const float rstd = rsqrtf(var + 1e-5f);
        float* orow = outp + ((long)(b*S_LEN + i))*HID + h*DHD + lr;
#pragma unroll
        for (int t = 0; t < 16; t++)
          orow[t*16] = (xv[t] - mean) * rstd * sc[t];
      }
    }
  }
}

extern "C" void kernel_launch(void* const* d_in, const int* in_sizes, int n_in,
                              void* d_out, int out_size, void* d_ws, size_t ws_size,
                              hipStream_t stream) {
  const float* q   = (const float*)d_in[0];
  const float* k   = (const float*)d_in[1];
  const float* v   = (const float*)d_in[2];
  const float* wi  = (const float*)d_in[3];
  const float* bi  = (const float*)d_in[4];
  const float* wf  = (const float*)d_in[5];
  const float* bf_ = (const float*)d_in[6];
  const float* lns = (const float*)d_in[7];
  float* outp = (float*)d_out;

  char* ws = (char*)d_ws;
  const long nelem = (long)BH_CNT * S_LEN * DHD;      // 4,194,304
  short* Kg  = (short*)ws;
  short* Vg  = Kg + nelem;
  float* igA = (float*)(ws + 2*nelem*sizeof(short));
  float* fgA = igA + (long)BATCH*S_LEN*NHEAD;
  float* aA  = fgA + (long)BATCH*S_LEN*NHEAD;
  float* mA  = aA + (long)BH_CNT*S_LEN;
  float* nfA = mA + (long)BH_CNT*S_LEN;

  // zero the gate accumulators (igA and fgA are contiguous)
  hipMemsetAsync(igA, 0, 2 * (size_t)BATCH*S_LEN*NHEAD * sizeof(float), stream);

  prep_kernel<<<2560, 256, 0, stream>>>(q, k, v, wi, wf, Kg, Vg, igA, fgA);
  scan_kernel<<<BH_CNT, 256, 0, stream>>>(igA, fgA, bi, bf_, aA, mA, nfA);
  mlstm_main_kernel<<<BH_CNT*32, 256, 0, stream>>>(q, Kg, Vg, aA, mA, nfA, lns, outp);
}

// Round 13
// 114.563 us; speedup vs baseline: 1.9540x; 1.4482x over previous
//
#include <hip/hip_runtime.h>
#include <hip/hip_bf16.h>

// mLSTM parallel-stabilized cell, MI355X (gfx950).
// B=2, S=2048, H=1024, NH=4, DH=256.
// Identity: max_log_D[i] = cs[i] + m[i], m[i] = prefixmax(ig[j]-cs[j]);
// D[i][j] = exp(a[j]-m[i]), a[j] = ig[j]-cs[j], exponent always <= 0.
// R13: main+scan = R9 VERBATIM (best passing main, 82us). Prep rebuilt:
// gate projection as coalesced GEMV (wave = 4 rows x seg; lane-contiguous
// 16B weight reads — fixes R9-R12's 128B-strided 25%-utilization weight
// access), k-cast and v-transpose families unchanged (byte-identical).

#define S_LEN 2048
#define DHD   256
#define NHEAD 4
#define BATCH 2
#define HID   1024
#define BH_CNT (BATCH*NHEAD)

typedef __attribute__((ext_vector_type(8))) short bf16x8;
typedef __attribute__((ext_vector_type(4))) short short4v;
typedef __attribute__((ext_vector_type(4))) float f32x4;

static __device__ __forceinline__ short f2b(float f) {
  __hip_bfloat16 h = __float2bfloat16(f);
  return *reinterpret_cast<short*>(&h);
}

static __device__ __forceinline__ bf16x8 pack8(f32x4 a, f32x4 b) {
  bf16x8 o;
  o[0]=f2b(a[0]); o[1]=f2b(a[1]); o[2]=f2b(a[2]); o[3]=f2b(a[3]);
  o[4]=f2b(b[0]); o[5]=f2b(b[1]); o[6]=f2b(b[2]); o[7]=f2b(b[3]);
  return o;
}

// async global->LDS DMA, 16B/lane. ldsdst wave-uniform; lane l -> dst + l*16B.
static __device__ __forceinline__ void gload16(const void* src, void* ldsdst) {
  __builtin_amdgcn_global_load_lds(
      (const __attribute__((address_space(1))) void*)src,
      (__attribute__((address_space(3))) void*)ldsdst, 16, 0, 0);
}

// ---- kernel 1 (prep): grid 3328 x 256.
// bx <  768 : gate GEMV — wave = (4 rows, seg); lane-coalesced weight reads
// bx < 2816 : k cast->Kg (swizzled), byte-identical to R11
// bx < 3328 : v transpose->Vg (swizzled), verbatim R11
// Kg tile [bh][jt][32x256]: (r,d) at r*256 + (d ^ ((r&7)<<3)).
// Vg tile [bh][jt][256x32]: (d,j) at d*32 + (j ^ (((d>>1)&3)<<3)).
__global__ __launch_bounds__(256) void prep_kernel(
    const float* __restrict__ q, const float* __restrict__ k, const float* __restrict__ v,
    const float* __restrict__ wi, const float* __restrict__ wf,
    short* __restrict__ Kg, short* __restrict__ Vg,
    float* __restrict__ igA, float* __restrict__ fgA) {
  __shared__ short vt2[32][264];
  const int bx = blockIdx.x, t = threadIdx.x;
  if (bx < 768) {
    // ---- gates: 4 waves/block; wave gw = (rows rg*4..rg*4+3, segment seg) ----
    const int w = t >> 6, lane = t & 63;
    const int gw = bx*4 + w;             // 0..3071
    const int seg = gw % 3;
    const int rg = gw / 3;               // 0..1023 -> rows rg*4..rg*4+3
    const float* xp = (seg == 0) ? q : (seg == 1) ? k : v;
    const float* wip = wi + (long)seg*HID*NHEAD;
    const float* wfp = wf + (long)seg*HID*NHEAD;
    f32x4 ai[4], af[4];
#pragma unroll
    for (int r = 0; r < 4; r++) { ai[r] = f32x4{0,0,0,0}; af[r] = f32x4{0,0,0,0}; }
    for (int cb = 0; cb < HID; cb += 64) {
      const int c = cb + lane;
      const f32x4 wiv = *(const f32x4*)(wip + (long)c*NHEAD);  // lane-contiguous 16B
      const f32x4 wfv = *(const f32x4*)(wfp + (long)c*NHEAD);
#pragma unroll
      for (int r = 0; r < 4; r++) {
        const float x = xp[(long)(rg*4 + r)*HID + c];           // coalesced 4B
        ai[r] += x * wiv;
        af[r] += x * wfv;
      }
    }
#pragma unroll
    for (int mk = 32; mk >= 1; mk >>= 1)
#pragma unroll
      for (int r = 0; r < 4; r++)
#pragma unroll
        for (int e = 0; e < 4; e++) {
          ai[r][e] += __shfl_xor(ai[r][e], mk);
          af[r][e] += __shfl_xor(af[r][e], mk);
        }
    if (lane == 0) {
#pragma unroll
      for (int r = 0; r < 4; r++) {
        const long row = rg*4 + r;
#pragma unroll
        for (int e = 0; e < 4; e++) {
          unsafeAtomicAdd(&igA[row*NHEAD + e], ai[r][e]);
          unsafeAtomicAdd(&fgA[row*NHEAD + e], af[r][e]);
        }
      }
    }
  } else if (bx < 2816) {
    // ---- k cast -> Kg (swizzled), byte-identical to R11 ----
    const int kb = bx - 768;
    const int g_row = kb*2 + (t >> 7);
    const int col = (t & 127) * 8;
    const long off = (long)g_row*HID + col;
    const f32x4 xk0 = *(const f32x4*)(k + off);
    const f32x4 xk1 = *(const f32x4*)(k + off + 4);
    bf16x8 o = pack8(xk0, xk1);
    const int b = g_row >> 11, s = g_row & (S_LEN-1);
    const int hh = col >> 8, d = col & 255;
    const int bh = b*NHEAD + hh, jt = s >> 5, rr = s & 31;
    *(bf16x8*)(Kg + ((long)bh*64 + jt)*8192 + rr*256 + (d ^ ((rr & 7) << 3))) = o;
  } else {
    // ---- vectorized v transpose -> Vg (swizzled tiles), verbatim R11 ----
    const int t2 = bx - 2816;              // 0..511
    const int jt = t2 & 63, bhv = t2 >> 6;
    const int b = bhv >> 2, hh = bhv & 3;
    const int j0 = jt * 32;
    const int r0 = t >> 3, c0 = (t & 7) * 32;
    const float* vsrc = v + ((long)(b*S_LEN + j0 + r0))*HID + hh*DHD + c0;
#pragma unroll
    for (int i = 0; i < 4; i++) {
      f32x4 a  = *(const f32x4*)(vsrc + i*8);
      f32x4 bb = *(const f32x4*)(vsrc + i*8 + 4);
      *(bf16x8*)&vt2[r0][c0 + i*8] = pack8(a, bb);
    }
    __syncthreads();
    const long base = ((long)bhv*64 + jt) * 8192;
    const int j = t & 31, dg = t >> 5;
#pragma unroll
    for (int dd = 0; dd < 32; dd++) {
      const int d = dg*32 + dd;
      Vg[base + (long)d*32 + (j ^ (((d >> 1) & 3) << 3))] = vt2[j][d];
    }
  }
}

// ---- kernel 2: per-(b,h) scan (verbatim R9) ----
__global__ void scan_kernel(const float* __restrict__ ig, const float* __restrict__ fg,
                            const float* __restrict__ bi, const float* __restrict__ bf_,
                            float* __restrict__ a_out, float* __restrict__ m_out,
                            float* __restrict__ nf_out) {
  int bh = blockIdx.x, b = bh >> 2, h = bh & 3;
  int t = threadIdx.x;
  __shared__ float tot[256];
  long gbase = (long)b * S_LEN;
  const float biv = bi[h], bfv = bf_[h];
  float ls[8];
  float run = 0.f;
  for (int e = 0; e < 8; e++) {
    int s = t*8 + e;
    float x = fg[(gbase + s)*NHEAD + h] + bfv;
    float l = fminf(x, 0.f) - log1pf(expf(-fabsf(x)));  // stable log_sigmoid
    run += l; ls[e] = run;
  }
  tot[t] = run;
  __syncthreads();
  for (int off = 1; off < 256; off <<= 1) {
    float x = tot[t];
    if (t >= off) x += tot[t - off];
    __syncthreads();
    tot[t] = x;
    __syncthreads();
  }
  float offc = (t == 0) ? 0.f : tot[t-1];
  __syncthreads();
  float av[8], am[8], csv[8];
  float runm = -1e30f;
  for (int e = 0; e < 8; e++) {
    int s = t*8 + e;
    float cs = ls[e] + offc;
    csv[e] = cs;
    float a = (ig[(gbase + s)*NHEAD + h] + biv) - cs;
    av[e] = a;
    runm = fmaxf(runm, a);
    am[e] = runm;
  }
  tot[t] = runm;
  __syncthreads();
  for (int off = 1; off < 256; off <<= 1) {
    float x = tot[t];
    if (t >= off) x = fmaxf(x, tot[t - off]);
    __syncthreads();
    tot[t] = x;
    __syncthreads();
  }
  float offm = (t == 0) ? -1e30f : tot[t-1];
  long obase = (long)bh * S_LEN;
  for (int e = 0; e < 8; e++) {
    int s = t*8 + e;
    float mm = fmaxf(am[e], offm);
    a_out[obase + s]  = av[e];
    m_out[obase + s]  = mm;
    nf_out[obase + s] = expf(-(csv[e] + mm));
  }
}

// ---- kernel 3: main (verbatim R9, best passing). 256 blocks = (bh, it). ----
__global__ __launch_bounds__(256, 1) void mlstm_main_kernel(
    const float* __restrict__ q, const short* __restrict__ Kg, const short* __restrict__ Vg,
    const float* __restrict__ a_arr, const float* __restrict__ m_arr,
    const float* __restrict__ nf_arr, const float* __restrict__ lns,
    float* __restrict__ outp) {
  __shared__ alignas(16) short Kst[2][2][8192];   // [dbuf][parity][32k x 256d swz]
  __shared__ alignas(16) short Vst[2][2][8192];   // [dbuf][parity][256d x 32j swz]
  __shared__ alignas(16) short plds[4][16*36];
  const int w = threadIdx.x >> 6, lane = threadIdx.x & 63;
  const int lr = lane & 15, g = lane >> 4;
  const int rg2 = w >> 1, kp = w & 1;
  const int bh = blockIdx.x & 7, it = blockIdx.x >> 3;
  const int b = bh >> 2, h = bh & 3;
  const int R0 = it*64 + rg2*32;          // wave's first global row
  const long arow = (long)bh * S_LEN;
  const int np = it + 1;                  // periods (2 tiles each)
  const int ntw = it*2 + rg2 + 1;         // wave computes jt < ntw (parity kp)
  const f32x4 zz = {0.f,0.f,0.f,0.f};
  const int sw = (lr & 7) << 3;

  // Q fragments for the wave's 32 rows, cast inline from fp32 source
  bf16x8 qfa[8], qfb[8];
  const float* qsrc = q + ((long)(b*S_LEN + R0 + lr))*HID + h*DHD + g*8;
#pragma unroll
  for (int c8 = 0; c8 < 8; c8++) {
    f32x4 u0 = *(const f32x4*)(qsrc + c8*32);
    f32x4 u1 = *(const f32x4*)(qsrc + c8*32 + 4);
    f32x4 w0 = *(const f32x4*)(qsrc + 16*HID + c8*32);
    f32x4 w1 = *(const f32x4*)(qsrc + 16*HID + c8*32 + 4);
    qfa[c8] = pack8(u0, u1);
    qfb[c8] = pack8(w0, w1);
  }
  float ma[4], mb[4];
#pragma unroll
  for (int r = 0; r < 4; r++) {
    ma[r] = m_arr[arow + R0 + g*4 + r];
    mb[r] = m_arr[arow + R0 + 16 + g*4 + r];
  }

  f32x4 oa[16], ob[16];
#pragma unroll
  for (int t = 0; t < 16; t++) { oa[t] = zz; ob[t] = zz; }
  float rs_a[4] = {0,0,0,0}, rs_b[4] = {0,0,0,0};
  short* myp = plds[w];

  // wave w stages one 16KB tile-buffer per period: w<2 -> K parity w, else V.
  auto STAGE = [&](int pb, int p) {
    const int jts = 2*p + (w & 1);
    short* dst = (w < 2) ? &Kst[pb][w & 1][0] : &Vst[pb][w & 1][0];
    const short* src = ((w < 2) ? Kg : Vg) + ((long)bh*64 + jts)*8192 + lane*8;
#pragma unroll
    for (int u = 0; u < 16; u++)
      gload16(src + u*512, dst + u*512);
  };

  float aC0, aC1, aN0 = 0.f, aN1 = 0.f;
  STAGE(0, 0);
  { const int j0 = kp*32;
    aC0 = a_arr[arow + j0 + lr]; aC1 = a_arr[arow + j0 + 16 + lr]; }

  for (int p = 0; p < np; ++p) {
    const int pb = p & 1;
    if (p + 1 < np) {
      STAGE(pb ^ 1, p + 1);
      { const int j0 = (2*(p+1) + kp)*32;
        aN0 = a_arr[arow + j0 + lr]; aN1 = a_arr[arow + j0 + 16 + lr]; }
      asm volatile("s_waitcnt vmcnt(16)" ::: "memory");  // own 16 DMA of tile p done
    } else {
      asm volatile("s_waitcnt vmcnt(0)" ::: "memory");
    }
    __builtin_amdgcn_s_barrier();

    const int jtc = 2*p + kp;
    if (jtc < ntw) {
      const int j0 = jtc*32;
      const short* Kt = &Kst[pb][kp][0];
      const short* Vt = &Vst[pb][kp][0];
      f32x4 s0a = zz, s1a = zz, s0b = zz, s1b = zz;
      __builtin_amdgcn_s_setprio(1);
#pragma unroll
      for (int c8 = 0; c8 < 8; c8++) {
        const int ko = lr*256 + ((c8*32 + g*8) ^ sw);
        bf16x8 k0 = *(const bf16x8*)&Kt[ko];
        bf16x8 k1 = *(const bf16x8*)&Kt[ko + 4096];
        s0a = __builtin_amdgcn_mfma_f32_16x16x32_bf16(qfa[c8], k0, s0a, 0, 0, 0);
        s0b = __builtin_amdgcn_mfma_f32_16x16x32_bf16(qfb[c8], k0, s0b, 0, 0, 0);
        s1a = __builtin_amdgcn_mfma_f32_16x16x32_bf16(qfa[c8], k1, s1a, 0, 0, 0);
        s1b = __builtin_amdgcn_mfma_f32_16x16x32_bf16(qfb[c8], k1, s1b, 0, 0, 0);
      }
      __builtin_amdgcn_s_setprio(0);
      // ---- group a: P + re-fragment ----
      bf16x8 pa_a, pa_b;
      {
        const bool needmask = (j0 + 31 > R0);
#pragma unroll
        for (int r = 0; r < 4; r++) {
          const int i = R0 + g*4 + r;
          float p0 = s0a[r] * 0.0625f * __expf(aC0 - ma[r]);
          float p1 = s1a[r] * 0.0625f * __expf(aC1 - ma[r]);
          if (needmask) {
            if (j0 + lr > i)      p0 = 0.f;
            if (j0 + 16 + lr > i) p1 = 0.f;
          }
          rs_a[r] += p0 + p1;
          myp[(g*4 + r)*36 + lr]      = f2b(p0);
          myp[(g*4 + r)*36 + 16 + lr] = f2b(p1);
        }
        const short* rp = myp + lr*36 + g*8;
        short4v plo = *(const short4v*)rp;
        short4v phi = *(const short4v*)(rp + 4);
        pa_a = bf16x8{plo[0],plo[1],plo[2],plo[3],phi[0],phi[1],phi[2],phi[3]};
      }
      // ---- group b ----
      {
        const bool needmask = (j0 + 31 > R0 + 16);
#pragma unroll
        for (int r = 0; r < 4; r++) {
          const int i = R0 + 16 + g*4 + r;
          float p0 = s0b[r] * 0.0625f * __expf(aC0 - mb[r]);
          float p1 = s1b[r] * 0.0625f * __expf(aC1 - mb[r]);
          if (needmask) {
            if (j0 + lr > i)      p0 = 0.f;
            if (j0 + 16 + lr > i) p1 = 0.f;
          }
          rs_b[r] += p0 + p1;
          myp[(g*4 + r)*36 + lr]      = f2b(p0);
          myp[(g*4 + r)*36 + 16 + lr] = f2b(p1);
        }
        const short* rp = myp + lr*36 + g*8;
        short4v plo = *(const short4v*)rp;
        short4v phi = *(const short4v*)(rp + 4);
        pa_b = bf16x8{plo[0],plo[1],plo[2],plo[3],phi[0],phi[1],phi[2],phi[3]};
      }
      // ---- PV: read each V fragment ONCE, feed both row groups ----
      __builtin_amdgcn_s_setprio(1);
#pragma unroll
      for (int t = 0; t < 16; t++) {
        const int d = t*16 + lr;
        const int vo = d*32 + ((g*8) ^ (((d >> 1) & 3) << 3));
        bf16x8 vf = *(const bf16x8*)&Vt[vo];
        oa[t] = __builtin_amdgcn_mfma_f32_16x16x32_bf16(pa_a, vf, oa[t], 0, 0, 0);
        ob[t] = __builtin_amdgcn_mfma_f32_16x16x32_bf16(pa_b, vf, ob[t], 0, 0, 0);
      }
      __builtin_amdgcn_s_setprio(0);
    }
    __builtin_amdgcn_s_barrier();
    if (p + 1 < np) { aC0 = aN0; aC1 = aN1; }
  }

  // ---- rowsum reduce over the 16 key-columns ----
#pragma unroll
  for (int r = 0; r < 4; r++)
    for (int mk = 1; mk < 16; mk <<= 1) {
      rs_a[r] += __shfl_xor(rs_a[r], mk);
      rs_b[r] += __shfl_xor(rs_b[r], mk);
    }

  // ---- combine key-parities via LDS (kp=1 writes, kp=0 reduces + LN) ----
  float* Ols = (float*)&Kst[0][0][0];   // 64 rows x 256 d fp32 = 64 KB
  float* rsl = (float*)&Vst[0][0][0];   // 64 rowsums
  __syncthreads();
  if (kp == 1) {
#pragma unroll
    for (int r = 0; r < 4; r++) {
      const int rla = rg2*32 + g*4 + r, rlb = rla + 16;
#pragma unroll
      for (int t = 0; t < 16; t++) {
        Ols[(long)rla*256 + t*16 + lr] = oa[t][r];
        Ols[(long)rlb*256 + t*16 + lr] = ob[t][r];
      }
      if (lr == 0) { rsl[rla] = rs_a[r]; rsl[rlb] = rs_b[r]; }
    }
  }
  __syncthreads();
  if (kp == 0) {
    float sc[16];
#pragma unroll
    for (int t = 0; t < 16; t++) sc[t] = lns[h*DHD + t*16 + lr];
    for (int grp = 0; grp < 2; grp++) {
      f32x4* acc = grp ? ob : oa;
      float* rsv = grp ? rs_b : rs_a;
#pragma unroll
      for (int r = 0; r < 4; r++) {
        const int rl = rg2*32 + grp*16 + g*4 + r;
        const int i = R0 + grp*16 + g*4 + r;
        const float rst = rsv[r] + rsl[rl];
        const float nfv = nf_arr[arow + i];
        const float inv = 1.f / (fmaxf(fabsf(rst), nfv) + 1e-6f);
        float sum = 0.f, sq = 0.f;
        float xv[16];
#pragma unroll
        for (int t = 0; t < 16; t++) {
          float x = (acc[t][r] + Ols[(long)rl*256 + t*16 + lr]) * inv;
          xv[t] = x; sum += x; sq += x*x;
        }
        for (int mk = 1; mk < 16; mk <<= 1) {
          sum += __shfl_xor(sum, mk);
          sq  += __shfl_xor(sq,  mk);
        }
        const float mean = sum * (1.f/256.f);
        const float var  = sq * (1.f/256.f) - mean*mean;
        const float rstd = rsqrtf(var + 1e-5f);
        float* orow = outp + ((long)(b*S_LEN + i))*HID + h*DHD + lr;
#pragma unroll
        for (int t = 0; t < 16; t++)
          orow[t*16] = (xv[t] - mean) * rstd * sc[t];
      }
    }
  }
}

extern "C" void kernel_launch(void* const* d_in, const int* in_sizes, int n_in,
                              void* d_out, int out_size, void* d_ws, size_t ws_size,
                              hipStream_t stream) {
  const float* q   = (const float*)d_in[0];
  const float* k   = (const float*)d_in[1];
  const float* v   = (const float*)d_in[2];
  const float* wi  = (const float*)d_in[3];
  const float* bi  = (const float*)d_in[4];
  const float* wf  = (const float*)d_in[5];
  const float* bf_ = (const float*)d_in[6];
  const float* lns = (const float*)d_in[7];
  float* outp = (float*)d_out;

  char* ws = (char*)d_ws;
  const long nelem = (long)BH_CNT * S_LEN * DHD;      // 4,194,304
  short* Kg  = (short*)ws;
  short* Vg  = Kg + nelem;
  float* igA = (float*)(ws + 2*nelem*sizeof(short));
  float* fgA = igA + (long)BATCH*S_LEN*NHEAD;
  float* aA  = fgA + (long)BATCH*S_LEN*NHEAD;
  float* mA  = aA + (long)BH_CNT*S_LEN;
  float* nfA = mA + (long)BH_CNT*S_LEN;

  // zero the gate accumulators (igA and fgA are contiguous)
  hipMemsetAsync(igA, 0, 2 * (size_t)BATCH*S_LEN*NHEAD * sizeof(float), stream);

  prep_kernel<<<3328, 256, 0, stream>>>(q, k, v, wi, wf, Kg, Vg, igA, fgA);
  scan_kernel<<<BH_CNT, 256, 0, stream>>>(igA, fgA, bi, bf_, aA, mA, nfA);
  mlstm_main_kernel<<<BH_CNT*32, 256, 0, stream>>>(q, Kg, Vg, aA, mA, nfA, lns, outp);
}

// Round 14
// 110.813 us; speedup vs baseline: 2.0201x; 1.0338x over previous
//
#include <hip/hip_runtime.h>
#include <hip/hip_bf16.h>

// mLSTM parallel-stabilized cell, MI355X (gfx950).
// B=2, S=2048, H=1024, NH=4, DH=256.
// Identity: max_log_D[i] = cs[i] + m[i], m[i] = prefixmax(ig[j]-cs[j]);
// D[i][j] = exp(a[j]-m[i]), a[j] = ig[j]-cs[j], exponent always <= 0.
// R14: main split by key PARITY across blocks (512 blocks, 2 blocks/CU,
// LDS 70KB): block = (bh, it, pi); 4 waves = 4 row groups of 16; per period
// stage ONE 32-key K+V tile (dbuf, vmcnt(8)); R10-proven atomic epilogue +
// finalize. CU pairing (pi=0,it=31-q)+(pi=1,it=q) = uniform 33 half-periods.
// Prep = R13 (coalesced gate GEMV), scan = R9.

#define S_LEN 2048
#define DHD   256
#define NHEAD 4
#define BATCH 2
#define HID   1024
#define BH_CNT (BATCH*NHEAD)

typedef __attribute__((ext_vector_type(8))) short bf16x8;
typedef __attribute__((ext_vector_type(4))) short short4v;
typedef __attribute__((ext_vector_type(4))) float f32x4;

static __device__ __forceinline__ short f2b(float f) {
  __hip_bfloat16 h = __float2bfloat16(f);
  return *reinterpret_cast<short*>(&h);
}

static __device__ __forceinline__ bf16x8 pack8(f32x4 a, f32x4 b) {
  bf16x8 o;
  o[0]=f2b(a[0]); o[1]=f2b(a[1]); o[2]=f2b(a[2]); o[3]=f2b(a[3]);
  o[4]=f2b(b[0]); o[5]=f2b(b[1]); o[6]=f2b(b[2]); o[7]=f2b(b[3]);
  return o;
}

// async global->LDS DMA, 16B/lane. ldsdst wave-uniform; lane l -> dst + l*16B.
static __device__ __forceinline__ void gload16(const void* src, void* ldsdst) {
  __builtin_amdgcn_global_load_lds(
      (const __attribute__((address_space(1))) void*)src,
      (__attribute__((address_space(3))) void*)ldsdst, 16, 0, 0);
}

// ---- kernel 1 (prep): grid 3328 x 256. (verbatim R13)
// bx <  768 : gate GEMV — wave = (4 rows, seg); lane-coalesced weight reads
// bx < 2816 : k cast->Kg (swizzled)
// bx < 3328 : v transpose->Vg (swizzled)
// Kg tile [bh][jt][32x256]: (r,d) at r*256 + (d ^ ((r&7)<<3)).
// Vg tile [bh][jt][256x32]: (d,j) at d*32 + (j ^ (((d>>1)&3)<<3)).
__global__ __launch_bounds__(256) void prep_kernel(
    const float* __restrict__ q, const float* __restrict__ k, const float* __restrict__ v,
    const float* __restrict__ wi, const float* __restrict__ wf,
    short* __restrict__ Kg, short* __restrict__ Vg,
    float* __restrict__ igA, float* __restrict__ fgA) {
  __shared__ short vt2[32][264];
  const int bx = blockIdx.x, t = threadIdx.x;
  if (bx < 768) {
    const int w = t >> 6, lane = t & 63;
    const int gw = bx*4 + w;             // 0..3071
    const int seg = gw % 3;
    const int rg = gw / 3;               // 0..1023 -> rows rg*4..rg*4+3
    const float* xp = (seg == 0) ? q : (seg == 1) ? k : v;
    const float* wip = wi + (long)seg*HID*NHEAD;
    const float* wfp = wf + (long)seg*HID*NHEAD;
    f32x4 ai[4], af[4];
#pragma unroll
    for (int r = 0; r < 4; r++) { ai[r] = f32x4{0,0,0,0}; af[r] = f32x4{0,0,0,0}; }
    for (int cb = 0; cb < HID; cb += 64) {
      const int c = cb + lane;
      const f32x4 wiv = *(const f32x4*)(wip + (long)c*NHEAD);
      const f32x4 wfv = *(const f32x4*)(wfp + (long)c*NHEAD);
#pragma unroll
      for (int r = 0; r < 4; r++) {
        const float x = xp[(long)(rg*4 + r)*HID + c];
        ai[r] += x * wiv;
        af[r] += x * wfv;
      }
    }
#pragma unroll
    for (int mk = 32; mk >= 1; mk >>= 1)
#pragma unroll
      for (int r = 0; r < 4; r++)
#pragma unroll
        for (int e = 0; e < 4; e++) {
          ai[r][e] += __shfl_xor(ai[r][e], mk);
          af[r][e] += __shfl_xor(af[r][e], mk);
        }
    if (lane == 0) {
#pragma unroll
      for (int r = 0; r < 4; r++) {
        const long row = rg*4 + r;
#pragma unroll
        for (int e = 0; e < 4; e++) {
          unsafeAtomicAdd(&igA[row*NHEAD + e], ai[r][e]);
          unsafeAtomicAdd(&fgA[row*NHEAD + e], af[r][e]);
        }
      }
    }
  } else if (bx < 2816) {
    const int kb = bx - 768;
    const int g_row = kb*2 + (t >> 7);
    const int col = (t & 127) * 8;
    const long off = (long)g_row*HID + col;
    const f32x4 xk0 = *(const f32x4*)(k + off);
    const f32x4 xk1 = *(const f32x4*)(k + off + 4);
    bf16x8 o = pack8(xk0, xk1);
    const int b = g_row >> 11, s = g_row & (S_LEN-1);
    const int hh = col >> 8, d = col & 255;
    const int bh = b*NHEAD + hh, jt = s >> 5, rr = s & 31;
    *(bf16x8*)(Kg + ((long)bh*64 + jt)*8192 + rr*256 + (d ^ ((rr & 7) << 3))) = o;
  } else {
    const int t2 = bx - 2816;              // 0..511
    const int jt = t2 & 63, bhv = t2 >> 6;
    const int b = bhv >> 2, hh = bhv & 3;
    const int j0 = jt * 32;
    const int r0 = t >> 3, c0 = (t & 7) * 32;
    const float* vsrc = v + ((long)(b*S_LEN + j0 + r0))*HID + hh*DHD + c0;
#pragma unroll
    for (int i = 0; i < 4; i++) {
      f32x4 a  = *(const f32x4*)(vsrc + i*8);
      f32x4 bb = *(const f32x4*)(vsrc + i*8 + 4);
      *(bf16x8*)&vt2[r0][c0 + i*8] = pack8(a, bb);
    }
    __syncthreads();
    const long base = ((long)bhv*64 + jt) * 8192;
    const int j = t & 31, dg = t >> 5;
#pragma unroll
    for (int dd = 0; dd < 32; dd++) {
      const int d = dg*32 + dd;
      Vg[base + (long)d*32 + (j ^ (((d >> 1) & 3) << 3))] = vt2[j][d];
    }
  }
}

// ---- kernel 2: per-(b,h) scan (verbatim R9) ----
__global__ void scan_kernel(const float* __restrict__ ig, const float* __restrict__ fg,
                            const float* __restrict__ bi, const float* __restrict__ bf_,
                            float* __restrict__ a_out, float* __restrict__ m_out,
                            float* __restrict__ nf_out) {
  int bh = blockIdx.x, b = bh >> 2, h = bh & 3;
  int t = threadIdx.x;
  __shared__ float tot[256];
  long gbase = (long)b * S_LEN;
  const float biv = bi[h], bfv = bf_[h];
  float ls[8];
  float run = 0.f;
  for (int e = 0; e < 8; e++) {
    int s = t*8 + e;
    float x = fg[(gbase + s)*NHEAD + h] + bfv;
    float l = fminf(x, 0.f) - log1pf(expf(-fabsf(x)));  // stable log_sigmoid
    run += l; ls[e] = run;
  }
  tot[t] = run;
  __syncthreads();
  for (int off = 1; off < 256; off <<= 1) {
    float x = tot[t];
    if (t >= off) x += tot[t - off];
    __syncthreads();
    tot[t] = x;
    __syncthreads();
  }
  float offc = (t == 0) ? 0.f : tot[t-1];
  __syncthreads();
  float av[8], am[8], csv[8];
  float runm = -1e30f;
  for (int e = 0; e < 8; e++) {
    int s = t*8 + e;
    float cs = ls[e] + offc;
    csv[e] = cs;
    float a = (ig[(gbase + s)*NHEAD + h] + biv) - cs;
    av[e] = a;
    runm = fmaxf(runm, a);
    am[e] = runm;
  }
  tot[t] = runm;
  __syncthreads();
  for (int off = 1; off < 256; off <<= 1) {
    float x = tot[t];
    if (t >= off) x = fmaxf(x, tot[t - off]);
    __syncthreads();
    tot[t] = x;
    __syncthreads();
  }
  float offm = (t == 0) ? -1e30f : tot[t-1];
  long obase = (long)bh * S_LEN;
  for (int e = 0; e < 8; e++) {
    int s = t*8 + e;
    float mm = fmaxf(am[e], offm);
    a_out[obase + s]  = av[e];
    m_out[obase + s]  = mm;
    nf_out[obase + s] = expf(-(csv[e] + mm));
  }
}

// ---- kernel 3: partial main. 512 blocks = (bh, it, parity pi).
// 4 waves = 4 row groups of 16; per period one 32-key tile (parity pi),
// dbuf staging quartered across waves, vmcnt(8); atomic O/rowsum epilogue.
// Block order: idx<256 -> (pi=0, it=31-(idx>>3)); else (pi=1, it=(idx-256)>>3)
// so CU c pairs np=(32-q)+(q+1)=33 periods — uniform load.
__global__ __launch_bounds__(256, 2) void mlstm_partial_kernel(
    const float* __restrict__ q, const short* __restrict__ Kg, const short* __restrict__ Vg,
    const float* __restrict__ a_arr, const float* __restrict__ m_arr,
    float* __restrict__ outp, float* __restrict__ rsacc) {
  __shared__ alignas(16) short Kst[2][8192];   // [dbuf][32k x 256d swz]
  __shared__ alignas(16) short Vst[2][8192];   // [dbuf][256d x 32j swz]
  __shared__ alignas(16) short plds[4][16*36];
  const int w = threadIdx.x >> 6, lane = threadIdx.x & 63;
  const int lr = lane & 15, g = lane >> 4;
  int pi, it, bh;
  if (blockIdx.x < 256) { pi = 0; bh = blockIdx.x & 7; it = 31 - (int)(blockIdx.x >> 3); }
  else { const int j = blockIdx.x - 256; pi = 1; bh = j & 7; it = j >> 3; }
  const int b = bh >> 2, h = bh & 3;
  const int R0 = it*64 + w*16;            // wave's 16 rows
  const long arow = (long)bh * S_LEN;
  const int np = it + 1;                  // staged periods (tiles 2p+pi)
  const int dmax = 2*it + (w >> 1) - pi;
  const int pmax = (dmax >= 0) ? (dmax >> 1) : -1;   // wave computes p <= pmax
  const f32x4 zz = {0.f,0.f,0.f,0.f};
  const int sw = (lr & 7) << 3;

  // Q fragments for the wave's 16 rows, cast inline from fp32 source
  bf16x8 qf[8];
  const float* qsrc = q + ((long)(b*S_LEN + R0 + lr))*HID + h*DHD + g*8;
#pragma unroll
  for (int c8 = 0; c8 < 8; c8++) {
    f32x4 u0 = *(const f32x4*)(qsrc + c8*32);
    f32x4 u1 = *(const f32x4*)(qsrc + c8*32 + 4);
    qf[c8] = pack8(u0, u1);
  }
  float mrow[4];
#pragma unroll
  for (int r = 0; r < 4; r++) mrow[r] = m_arr[arow + R0 + g*4 + r];

  f32x4 oacc[16];
#pragma unroll
  for (int t = 0; t < 16; t++) oacc[t] = zz;
  float rs[4] = {0.f,0.f,0.f,0.f};
  short* myp = plds[w];

  // wave w stages quarter w of the K tile and quarter w of the V tile (8 DMA)
  auto STAGE = [&](int pb, int p) {
    const int jts = 2*p + pi;
    const long toff = ((long)bh*64 + jts)*8192 + w*2048 + lane*8;
    short* kdst = &Kst[pb][w*2048];
    short* vdst = &Vst[pb][w*2048];
    const short* ksrc = Kg + toff;
    const short* vsrc = Vg + toff;
#pragma unroll
    for (int u = 0; u < 4; u++) gload16(ksrc + u*512, kdst + u*512);
#pragma unroll
    for (int u = 0; u < 4; u++) gload16(vsrc + u*512, vdst + u*512);
  };

  float aC0, aC1, aN0 = 0.f, aN1 = 0.f;
  STAGE(0, 0);
  { const int j0 = pi*32;
    aC0 = a_arr[arow + j0 + lr]; aC1 = a_arr[arow + j0 + 16 + lr]; }

  for (int p = 0; p < np; ++p) {
    const int pb = p & 1;
    if (p + 1 < np) {
      STAGE(pb ^ 1, p + 1);
      { const int j0 = (2*(p+1) + pi)*32;
        aN0 = a_arr[arow + j0 + lr]; aN1 = a_arr[arow + j0 + 16 + lr]; }
      asm volatile("s_waitcnt vmcnt(8)" ::: "memory");  // own 8 DMA of tile p (+2 a) done
    } else {
      asm volatile("s_waitcnt vmcnt(0)" ::: "memory");
    }
    __builtin_amdgcn_s_barrier();

    if (p <= pmax) {
      const int j0 = (2*p + pi)*32;
      const short* Kt = &Kst[pb][0];
      const short* Vt = &Vst[pb][0];
      f32x4 s0 = zz, s1 = zz;
      __builtin_amdgcn_s_setprio(1);
#pragma unroll
      for (int c8 = 0; c8 < 8; c8++) {
        const int ko = lr*256 + ((c8*32 + g*8) ^ sw);
        bf16x8 k0 = *(const bf16x8*)&Kt[ko];
        bf16x8 k1 = *(const bf16x8*)&Kt[ko + 4096];
        s0 = __builtin_amdgcn_mfma_f32_16x16x32_bf16(qf[c8], k0, s0, 0, 0, 0);
        s1 = __builtin_amdgcn_mfma_f32_16x16x32_bf16(qf[c8], k1, s1, 0, 0, 0);
      }
      __builtin_amdgcn_s_setprio(0);
      const bool needmask = (j0 + 31 > R0);
#pragma unroll
      for (int r = 0; r < 4; r++) {
        const int i = R0 + g*4 + r;
        float p0 = s0[r] * 0.0625f * __expf(aC0 - mrow[r]);
        float p1 = s1[r] * 0.0625f * __expf(aC1 - mrow[r]);
        if (needmask) {               // causal mask, diagonal tiles only
          if (j0 + lr > i)      p0 = 0.f;
          if (j0 + 16 + lr > i) p1 = 0.f;
        }
        rs[r] += p0 + p1;
        myp[(g*4 + r)*36 + lr]      = f2b(p0);
        myp[(g*4 + r)*36 + 16 + lr] = f2b(p1);
      }
      // re-fragment P (C-layout) -> A-layout via per-wave LDS
      const short* rp = myp + lr*36 + g*8;
      short4v plo = *(const short4v*)rp;
      short4v phi = *(const short4v*)(rp + 4);
      bf16x8 pa = {plo[0],plo[1],plo[2],plo[3],phi[0],phi[1],phi[2],phi[3]};
      __builtin_amdgcn_s_setprio(1);
#pragma unroll
      for (int t = 0; t < 16; t++) {
        const int d = t*16 + lr;
        const int vo = d*32 + ((g*8) ^ (((d >> 1) & 3) << 3));
        bf16x8 vf = *(const bf16x8*)&Vt[vo];
        oacc[t] = __builtin_amdgcn_mfma_f32_16x16x32_bf16(pa, vf, oacc[t], 0, 0, 0);
      }
      __builtin_amdgcn_s_setprio(0);
    }
    __builtin_amdgcn_s_barrier();
    if (p + 1 < np) { aC0 = aN0; aC1 = aN1; }
  }

  // rowsum reduce over the 16 key-columns
#pragma unroll
  for (int r = 0; r < 4; r++)
    for (int mk = 1; mk < 16; mk <<= 1)
      rs[r] += __shfl_xor(rs[r], mk);

  // atomic-accumulate partial O + rowsums (waves own disjoint rows; the
  // matching other-parity block adds the complement)
#pragma unroll
  for (int r = 0; r < 4; r++) {
    const int i = R0 + g*4 + r;
    float* orow = outp + ((long)(b*S_LEN + i))*HID + h*DHD + lr;
#pragma unroll
    for (int t = 0; t < 16; t++)
      unsafeAtomicAdd(orow + t*16, oacc[t][r]);
    if (lr == 0)
      unsafeAtomicAdd(&rsacc[arow + i], rs[r]);
  }
}

// ---- kernel 4: finalize — normalizer + per-head LayerNorm (verbatim R10) ----
__global__ __launch_bounds__(256) void finalize_kernel(
    float* __restrict__ outp, const float* __restrict__ rsacc,
    const float* __restrict__ nf_arr, const float* __restrict__ lns) {
  const int bi = blockIdx.x;                  // b*S + i
  const int h = threadIdx.x >> 6, lane = threadIdx.x & 63;
  const int b = bi >> 11, i = bi & (S_LEN-1);
  const int bh = b*NHEAD + h;
  const long roff = (long)bi * HID + (long)h*DHD;
  f32x4 xv = *(const f32x4*)(outp + roff + lane*4);
  const float rsv = rsacc[(long)bh*S_LEN + i];
  const float nfv = nf_arr[(long)bh*S_LEN + i];
  const float inv = 1.f / (fmaxf(fabsf(rsv), nfv) + 1e-6f);
  xv[0]*=inv; xv[1]*=inv; xv[2]*=inv; xv[3]*=inv;
  float sum = xv[0]+xv[1]+xv[2]+xv[3];
  float sq  = xv[0]*xv[0]+xv[1]*xv[1]+xv[2]*xv[2]+xv[3]*xv[3];
  for (int mk = 1; mk < 64; mk <<= 1) {
    sum += __shfl_xor(sum, mk);
    sq  += __shfl_xor(sq,  mk);
  }
  const float mean = sum * (1.f/256.f);
  const float var  = sq * (1.f/256.f) - mean*mean;
  const float rstd = rsqrtf(var + 1e-5f);
  f32x4 sc = *(const f32x4*)(lns + h*DHD + lane*4);
  f32x4 o;
  o[0]=(xv[0]-mean)*rstd*sc[0]; o[1]=(xv[1]-mean)*rstd*sc[1];
  o[2]=(xv[2]-mean)*rstd*sc[2]; o[3]=(xv[3]-mean)*rstd*sc[3];
  *(f32x4*)(outp + roff + lane*4) = o;
}

extern "C" void kernel_launch(void* const* d_in, const int* in_sizes, int n_in,
                              void* d_out, int out_size, void* d_ws, size_t ws_size,
                              hipStream_t stream) {
  const float* q   = (const float*)d_in[0];
  const float* k   = (const float*)d_in[1];
  const float* v   = (const float*)d_in[2];
  const float* wi  = (const float*)d_in[3];
  const float* bi  = (const float*)d_in[4];
  const float* wf  = (const float*)d_in[5];
  const float* bf_ = (const float*)d_in[6];
  const float* lns = (const float*)d_in[7];
  float* outp = (float*)d_out;

  char* ws = (char*)d_ws;
  const long nelem = (long)BH_CNT * S_LEN * DHD;      // 4,194,304
  short* Kg  = (short*)ws;
  short* Vg  = Kg + nelem;
  float* igA = (float*)(ws + 2*nelem*sizeof(short));
  float* fgA = igA + (long)BATCH*S_LEN*NHEAD;
  float* aA  = fgA + (long)BATCH*S_LEN*NHEAD;
  float* mA  = aA + (long)BH_CNT*S_LEN;
  float* nfA = mA + (long)BH_CNT*S_LEN;
  float* rsA = nfA + (long)BH_CNT*S_LEN;

  // zero accumulators: gates, output, rowsums
  hipMemsetAsync(igA, 0, 2 * (size_t)BATCH*S_LEN*NHEAD * sizeof(float), stream);
  hipMemsetAsync(outp, 0, (size_t)out_size * sizeof(float), stream);
  hipMemsetAsync(rsA, 0, (size_t)BH_CNT * S_LEN * sizeof(float), stream);

  prep_kernel<<<3328, 256, 0, stream>>>(q, k, v, wi, wf, Kg, Vg, igA, fgA);
  scan_kernel<<<BH_CNT, 256, 0, stream>>>(igA, fgA, bi, bf_, aA, mA, nfA);
  mlstm_partial_kernel<<<512, 256, 0, stream>>>(q, Kg, Vg, aA, mA, outp, rsA);
  finalize_kernel<<<BATCH*S_LEN, 256, 0, stream>>>(outp, rsA, nfA, lns);
}